// Round 3
// baseline (130.527 us; speedup 1.0000x reference)
//
#include <hip/hip_runtime.h>

#define LOG2E 1.4426950408889634f

typedef __bf16 bf16x8 __attribute__((ext_vector_type(8)));
typedef short s16x4 __attribute__((ext_vector_type(4)));
typedef float f32x4 __attribute__((ext_vector_type(4)));

#define BB 2
#define NN 2048
#define CC 384
#define NH 12
#define HD 32
#define MROWS (BB * NN)   /* 4096 */

__device__ __forceinline__ unsigned short f2bf(float f) {
  __bf16 h = (__bf16)f;
  return __builtin_bit_cast(unsigned short, h);
}

__device__ __forceinline__ bf16x8 ldg_bf8(const unsigned short* p) {
  uint4 v = *reinterpret_cast<const uint4*>(p);
  return __builtin_bit_cast(bf16x8, v);
}

// fast 2^x: raw v_exp_f32 (args here are bounded ~±48, no denorm fixup needed)
__device__ __forceinline__ float fexp2(float x) {
#if __has_builtin(__builtin_amdgcn_exp2f)
  return __builtin_amdgcn_exp2f(x);
#else
  return exp2f(x);
#endif
}

// pack 4 floats -> 4 bf16 via v_cvt_pk_bf16_f32 when available
__device__ __forceinline__ s16x4 pack_bf4(float a, float b, float c, float d) {
#if __has_builtin(__builtin_amdgcn_cvt_pk_bf16_f32)
  auto lo = __builtin_amdgcn_cvt_pk_bf16_f32(a, b);
  auto hi = __builtin_amdgcn_cvt_pk_bf16_f32(c, d);
  uint2 u = {__builtin_bit_cast(unsigned int, lo),
             __builtin_bit_cast(unsigned int, hi)};
  return __builtin_bit_cast(s16x4, u);
#else
  s16x4 r = {(short)f2bf(a), (short)f2bf(b), (short)f2bf(c), (short)f2bf(d)};
  return r;
#endif
}

// async global->LDS DMA, 16B per lane; LDS dest = wave-uniform base + lane*16
typedef __attribute__((address_space(1))) const void gas_void;
typedef __attribute__((address_space(3))) void las_void;
__device__ __forceinline__ void gload_lds16(const void* g, void* l) {
  __builtin_amdgcn_global_load_lds((gas_void*)(unsigned long long)g,
                                   (las_void*)(unsigned long long)l, 16, 0, 0);
}

__device__ __forceinline__ f32x4 mfma32(bf16x8 a, bf16x8 b, f32x4 c) {
  return __builtin_amdgcn_mfma_f32_16x16x32_bf16(a, b, c, 0, 0, 0);
}

// 16x16x16 bf16 MFMA (A,B = 4 bf16/lane: X[m|n=lane&15][k=(lane>>4)*4+j];
// C/D: row=(lane>>4)*4+r, col=lane&15). Host pass must not see the builtin.
__device__ __forceinline__ f32x4 mfma16(s16x4 a, s16x4 b, f32x4 c) {
#if defined(__HIP_DEVICE_COMPILE__)
#if __has_builtin(__builtin_amdgcn_mfma_f32_16x16x16bf16_1k)
  return __builtin_amdgcn_mfma_f32_16x16x16bf16_1k(a, b, c, 0, 0, 0);
#else
  asm volatile("v_mfma_f32_16x16x16_bf16 %0, %1, %2, %0"
               : "+v"(c) : "v"(a), "v"(b));
  return c;
#endif
#else
  return c;  // host type-check stub
#endif
}

// ------- prep: fp32->bf16 casts, 8 elems/thread (G13 vectorized) -------------
// Segments (elems): x 1572864 | q_w 147456 | kv_w 294912 | proj_w 147456 |
// pos_bias 24576. Total 2187264 = 1068 blocks * 256 thr * 8.
__global__ __launch_bounds__(256) void prep_kernel(
    const float* __restrict__ x, const float* __restrict__ q_w,
    const float* __restrict__ kv_w, const float* __restrict__ proj_w,
    const float* __restrict__ pos_bias, unsigned short* __restrict__ xb,
    unsigned short* __restrict__ qwb, unsigned short* __restrict__ kvwb,
    unsigned short* __restrict__ pwb, float* __restrict__ bias2) {
  long i = (long)(blockIdx.x * 256 + threadIdx.x) * 8;
  auto cast8 = [&](const float* s, unsigned short* d, long off) {
    float4 a = *reinterpret_cast<const float4*>(s + off);
    float4 b = *reinterpret_cast<const float4*>(s + off + 4);
    s16x4 lo = pack_bf4(a.x, a.y, a.z, a.w);
    s16x4 hi = pack_bf4(b.x, b.y, b.z, b.w);
    uint2 l = __builtin_bit_cast(uint2, lo), h = __builtin_bit_cast(uint2, hi);
    uint4 o = {l.x, l.y, h.x, h.y};
    *reinterpret_cast<uint4*>(d + off) = o;
  };
  if (i < 1572864) { cast8(x, xb, i); return; }
  i -= 1572864;
  if (i < 147456) { cast8(q_w, qwb, i); return; }
  i -= 147456;
  if (i < 294912) { cast8(kv_w, kvwb, i); return; }
  i -= 294912;
  if (i < 147456) { cast8(proj_w, pwb, i); return; }
  i -= 147456;
  float4 a = *reinterpret_cast<const float4*>(pos_bias + i);
  float4 b = *reinterpret_cast<const float4*>(pos_bias + i + 4);
  a.x *= LOG2E; a.y *= LOG2E; a.z *= LOG2E; a.w *= LOG2E;
  b.x *= LOG2E; b.y *= LOG2E; b.z *= LOG2E; b.w *= LOG2E;
  *reinterpret_cast<float4*>(bias2 + i) = a;
  *reinterpret_cast<float4*>(bias2 + i + 4) = b;
}

// ------- fused QKV GEMM + l2norm, LDS-staged (m97 structure + T2 swizzle) ----
// Grid (64, NH). Block tile 64M x 96N (head h: q|k|v 32-col slices), BK=64.
// LDS tiles are row-major [row][8 x 16B]; slot column XOR-swizzled by (row&7)
// via pre-permuted GLOBAL source (linear DMA dest, rule #21) so the fragment
// ds_read_b128 spreads 16 lanes over 8 bank-groups instead of 1.
__global__ __launch_bounds__(256, 4) void gemm_qkv_norm_kernel(
    const unsigned short* __restrict__ xb, const unsigned short* __restrict__ qwb,
    const unsigned short* __restrict__ kvwb, const float* __restrict__ q_b,
    const float* __restrict__ kv_b, const float* __restrict__ qe,
    const float* __restrict__ temperature, unsigned short* __restrict__ Qs,
    unsigned short* __restrict__ Kn, unsigned short* __restrict__ VT) {
  __shared__ alignas(16) char smem[2][20480];
  int wave = threadIdx.x >> 6, lane = threadIdx.x & 63;
  int c = lane & 15, quad = lane >> 4;
  int h = blockIdx.y;
  int m0b = blockIdx.x * 64;
  int cid = wave * 64 + lane;

  auto stage = [&](int buf, int kk) {
    char* base = smem[buf];
#pragma unroll
    for (int j = 0; j < 2; ++j) {  // A: 512 chunks (64 rows x 128B)
      int chunk = j * 256 + cid;
      int row = chunk >> 3, e = chunk & 7;
      gload_lds16(xb + (long)(m0b + row) * CC + kk + (e ^ (row & 7)) * 8,
                  base + j * 4096 + wave * 1024);
    }
#pragma unroll
    for (int j = 0; j < 3; ++j) {  // B: 768 chunks (96 rows x 128B)
      int chunk = j * 256 + cid;
      int row = chunk >> 3, e = chunk & 7;
      const unsigned short* src;
      if (row < 32)      src = qwb + (long)(h * 32 + row) * CC;
      else if (row < 64) src = kvwb + (long)(h * 32 + (row - 32)) * CC;
      else               src = kvwb + (long)(CC + h * 32 + (row - 64)) * CC;
      gload_lds16(src + kk + (e ^ (row & 7)) * 8,
                  base + 8192 + j * 4096 + wave * 1024);
    }
  };

  f32x4 acc[6] = {};
  auto compute = [&](int buf) {
    const char* base = smem[buf];
#pragma unroll
    for (int kh = 0; kh < 2; ++kh) {
      int sa = ((kh * 4 + quad) ^ (c & 7)) * 16;  // swizzled slot
      bf16x8 a = *(const bf16x8*)(base + (wave * 16 + c) * 128 + sa);
#pragma unroll
      for (int t = 0; t < 6; ++t) {
        bf16x8 b = *(const bf16x8*)(base + 8192 + (t * 16 + c) * 128 + sa);
        acc[t] = mfma32(a, b, acc[t]);
      }
    }
  };

  stage(0, 0);
#pragma unroll 1
  for (int s = 0; s < 6; ++s) {
    __syncthreads();
    if (s < 5) stage((s + 1) & 1, (s + 1) * 64);
    compute(s & 1);
  }

  // epilogue: bias + l2norm(q,k) + qe/scale + stores
  int m0 = m0b + wave * 16;
  float qb0 = q_b[h * 32 + c], qb1 = q_b[h * 32 + 16 + c];
  float kb0 = kv_b[h * 32 + c], kb1 = kv_b[h * 32 + 16 + c];
  float vb0 = kv_b[CC + h * 32 + c], vb1 = kv_b[CC + h * 32 + 16 + c];
  float qe0 = qe[h * HD + c], qe1 = qe[h * HD + 16 + c];
  float sc = log1pf(expf(temperature[h])) * 11.0f;  // softplus * log2(N)
  int b = m0 >> 11;
  int nb = (m0 & 2047) + quad * 4;
  int pair = b * NH + h;
  unsigned short* qsb = Qs + ((long)pair * NN + nb) * HD;
  unsigned short* knb = Kn + ((long)pair * NN + nb) * HD;
  ushort4 vp0, vp1;
#pragma unroll
  for (int r = 0; r < 4; ++r) {
    float q0 = acc[0][r] + qb0, q1 = acc[1][r] + qb1;
    float k0 = acc[2][r] + kb0, k1 = acc[3][r] + kb1;
    float v0 = acc[4][r] + vb0, v1 = acc[5][r] + vb1;
    float qs = q0 * q0 + q1 * q1, ks = k0 * k0 + k1 * k1;
#pragma unroll
    for (int off = 8; off; off >>= 1) {
      qs += __shfl_xor(qs, off);
      ks += __shfl_xor(ks, off);
    }
    float qi = 1.0f / fmaxf(sqrtf(qs), 1e-12f);
    float ki = 1.0f / fmaxf(sqrtf(ks), 1e-12f);
    qsb[r * HD + c] = f2bf((q0 * qi + qe0) * sc);
    qsb[r * HD + 16 + c] = f2bf((q1 * qi + qe1) * sc);
    knb[r * HD + c] = f2bf(k0 * ki);
    knb[r * HD + 16 + c] = f2bf(k1 * ki);
    ((unsigned short*)&vp0)[r] = f2bf(v0);
    ((unsigned short*)&vp1)[r] = f2bf(v1);
  }
  *reinterpret_cast<ushort4*>(VT + ((long)pair * HD + c) * NN + nb) = vp0;
  *reinterpret_cast<ushort4*>(VT + ((long)pair * HD + 16 + c) * NN + nb) = vp1;
}

// -------- attention: S^T form, 128-thread blocks, 32 q-rows per wave ---------
// Grid 768 x 128. 2 waves x 32 q-rows (TWO q-fragments each) = 64 q-rows/block;
// K-loop covers all 2048 rows in 16 double-buffered 128-row steps. Each K/V
// LDS read (kf, vlo, vhi) now feeds TWO q-fragments' MFMAs -> LDS read traffic
// per score halves vs 4-wave/1-frag (the per-CU LDS pipe was the bottleneck).
// LDS = 2x16KB tiles + 8KB bias = 40,960 B; 768 blocks = 3 resident blocks/CU.
__global__ __launch_bounds__(128, 2) void attn_kernel(
    const unsigned short* __restrict__ Qs, const unsigned short* __restrict__ Kn,
    const unsigned short* __restrict__ VT, const float* __restrict__ bias2,
    unsigned short* __restrict__ ao) {
  __shared__ alignas(16) char smem[2][16384];  // [buf][K 8KB | V 8KB]
  __shared__ alignas(16) char biasl[8192];
  int wave = threadIdx.x >> 6, lane = threadIdx.x & 63;
  int c = lane & 15, quad = lane >> 4;
  int id = blockIdx.x;
  int xcd = id & 7, rr = id >> 3;
  int pair = (rr >> 5) * 8 + xcd;   // 3 pairs per XCD
  int qt = rr & 31;
  int h = pair % NH, b = pair / NH;
  const unsigned short* Qp = Qs + (long)pair * NN * HD;
  const char* Kg0 = (const char*)(Kn + (long)pair * NN * HD);
  const char* Vg0 = (const char*)(VT + (long)pair * HD * NN);
  const char* bp = (const char*)(bias2 + h * NN);
  int q0 = qt * 64 + wave * 32;
  bf16x8 qfA = ldg_bf8(Qp + (long)(q0 + c) * HD + quad * 8);       // B-op frag A
  bf16x8 qfB = ldg_bf8(Qp + (long)(q0 + 16 + c) * HD + quad * 8);  // B-op frag B
  f32x4 o0A = {}, o1A = {}, o0B = {}, o1B = {};  // O^T: d=quad*4+r (+16), q=c
  float rsA = 0.f, rsB = 0.f;

  const int koff = (c * 4 + quad) * 16;  // K within-chunk source permutation

  // stage K-rows [i*128, i*128+128) into smem[buf]; 2 waves x 4 chunks each
  auto stage = [&](int buf, int i) {
    char* tb = smem[buf];
    long krow0 = (long)i * 128;
    const char* Kg = Kg0 + krow0 * (HD * 2);
    const char* Vg = Vg0 + krow0 * 2;
#pragma unroll
    for (int j = 0; j < 4; ++j) {
      int ck = wave * 4 + j;  // 0..7 K-chunks of 1KB
      gload_lds16(Kg + ck * 1024 + koff, tb + ck * 1024);
      int chunk = ck * 64 + lane;  // V: 512 x 16B chunks
      int d = chunk >> 4, e = chunk & 15;
      int es = e ^ (d & 15);  // within-row swizzle keeps source coalesced
      gload_lds16(Vg + (long)d * (NN * 2) + es * 16, tb + 8192 + ck * 1024);
    }
  };

  auto compute = [&](int buf, int i) {
    const char* kb = smem[buf] + lane * 16;  // lane-contig: conflict-free
    const char* vb = smem[buf] + 8192;
    const char* bl = biasl + i * 512 + quad * 16;
#pragma unroll
    for (int t8 = 0; t8 < 8; ++t8) {
      bf16x8 kf = *(const bf16x8*)(kb + t8 * 1024);
      f32x4 bbv = *(const f32x4*)(bl + t8 * 64);  // broadcast (free)
      f32x4 sA = mfma32(kf, qfA, bbv);  // S^T + bias via accumulator init
      f32x4 sB = mfma32(kf, qfB, bbv);
      float a0 = fexp2(sA[0]), a1 = fexp2(sA[1]);
      float a2 = fexp2(sA[2]), a3 = fexp2(sA[3]);
      float e0 = fexp2(sB[0]), e1 = fexp2(sB[1]);
      float e2 = fexp2(sB[2]), e3 = fexp2(sB[3]);
      rsA += (a0 + a1) + (a2 + a3);
      rsB += (e0 + e1) + (e2 + e3);
      s16x4 pfA = pack_bf4(a0, a1, a2, a3);
      s16x4 pfB = pack_bf4(e0, e1, e2, e3);
      int vsw = (((t8 * 2 + (quad >> 1)) ^ c) * 16) + (quad & 1) * 8;
      s16x4 vlo = *(const s16x4*)(vb + c * 256 + vsw);
      s16x4 vhi = *(const s16x4*)(vb + (c + 16) * 256 + vsw);
      o0A = mfma16(vlo, pfA, o0A);
      o1A = mfma16(vhi, pfA, o1A);
      o0B = mfma16(vlo, pfB, o0B);
      o1B = mfma16(vhi, pfB, o1B);
    }
  };

  // one-time bias stage (8KB, 4KB per wave) + first tile
#pragma unroll
  for (int j = 0; j < 4; ++j)
    gload_lds16(bp + wave * 4096 + j * 1024 + lane * 16,
                biasl + wave * 4096 + j * 1024);
  stage(0, 0);
#pragma unroll 1
  for (int i = 0; i < 16; ++i) {
    __syncthreads();
    if (i < 15) stage((i + 1) & 1, i + 1);
    compute(i & 1, i);
  }

  // per-lane row-sum for q=c (lanes c, c+16, c+32, c+48 hold the 4 k-quads)
  rsA += __shfl_xor(rsA, 16);
  rsA += __shfl_xor(rsA, 32);
  rsB += __shfl_xor(rsB, 16);
  rsB += __shfl_xor(rsB, 32);
  float invA = 1.0f / rsA;
  float invB = 1.0f / rsB;
  unsigned short* opA = ao + (long)(b * NN + q0 + c) * CC + h * HD + quad * 4;
  unsigned short* opB = ao + (long)(b * NN + q0 + 16 + c) * CC + h * HD + quad * 4;
  ushort4 sa0, sa1, sb0, sb1;
#pragma unroll
  for (int r = 0; r < 4; ++r) {
    ((unsigned short*)&sa0)[r] = f2bf(o0A[r] * invA);
    ((unsigned short*)&sa1)[r] = f2bf(o1A[r] * invA);
    ((unsigned short*)&sb0)[r] = f2bf(o0B[r] * invB);
    ((unsigned short*)&sb1)[r] = f2bf(o1B[r] * invB);
  }
  *reinterpret_cast<ushort4*>(opA) = sa0;
  *reinterpret_cast<ushort4*>(opA + 16) = sa1;
  *reinterpret_cast<ushort4*>(opB) = sb0;
  *reinterpret_cast<ushort4*>(opB + 16) = sb1;
}

// ---------------- proj: out = ao @ proj_w^T + proj_b, LDS-staged -------------
// Grid (64, 12). Block tile 64M x 32N, BK=64 -> 768 blocks = exactly 3/CU.
// LDS (8KB+4KB)x2 = 24KB. Same T2 swizzle as gemm_qkv.
__global__ __launch_bounds__(256, 4) void proj_kernel(
    const unsigned short* __restrict__ ab, const unsigned short* __restrict__ pwb,
    const float* __restrict__ proj_b, float* __restrict__ out) {
  __shared__ alignas(16) char smem[2][12288];
  int wave = threadIdx.x >> 6, lane = threadIdx.x & 63;
  int c = lane & 15, quad = lane >> 4;
  int m0b = blockIdx.x * 64;
  int n0 = blockIdx.y * 32;
  int cid = wave * 64 + lane;

  auto stage = [&](int buf, int kk) {
    char* base = smem[buf];
#pragma unroll
    for (int j = 0; j < 2; ++j) {  // A: 512 chunks (64 rows x 128B)
      int chunk = j * 256 + cid;
      int row = chunk >> 3, e = chunk & 7;
      gload_lds16(ab + (long)(m0b + row) * CC + kk + (e ^ (row & 7)) * 8,
                  base + j * 4096 + wave * 1024);
    }
    {  // B: 256 chunks (32 rows x 128B)
      int row = cid >> 3, e = cid & 7;
      gload_lds16(pwb + (long)(n0 + row) * CC + kk + (e ^ (row & 7)) * 8,
                  base + 8192 + wave * 1024);
    }
  };

  f32x4 acc[2] = {};
  auto compute = [&](int buf) {
    const char* base = smem[buf];
#pragma unroll
    for (int kh = 0; kh < 2; ++kh) {
      int sa = ((kh * 4 + quad) ^ (c & 7)) * 16;  // swizzled slot
      bf16x8 a = *(const bf16x8*)(base + (wave * 16 + c) * 128 + sa);
#pragma unroll
      for (int t = 0; t < 2; ++t) {
        bf16x8 b = *(const bf16x8*)(base + 8192 + (t * 16 + c) * 128 + sa);
        acc[t] = mfma32(a, b, acc[t]);
      }
    }
  };

  stage(0, 0);
#pragma unroll 1
  for (int s = 0; s < 6; ++s) {
    __syncthreads();
    if (s < 5) stage((s + 1) & 1, (s + 1) * 64);
    compute(s & 1);
  }

  int m0 = m0b + wave * 16;
#pragma unroll
  for (int t = 0; t < 2; ++t) {
    int o = n0 + t * 16 + c;
    float bv = proj_b[o];
#pragma unroll
    for (int r = 0; r < 4; ++r) {
      out[(long)(m0 + quad * 4 + r) * CC + o] = acc[t][r] + bv;
    }
  }
}

extern "C" void kernel_launch(void* const* d_in, const int* in_sizes, int n_in,
                              void* d_out, int out_size, void* d_ws, size_t ws_size,
                              hipStream_t stream) {
  const float* x = (const float*)d_in[0];
  const float* q_w = (const float*)d_in[1];
  const float* q_b = (const float*)d_in[2];
  const float* kv_w = (const float*)d_in[3];
  const float* kv_b = (const float*)d_in[4];
  const float* qe = (const float*)d_in[5];
  const float* temp = (const float*)d_in[6];
  const float* pos_bias = (const float*)d_in[7];
  const float* proj_w = (const float*)d_in[8];
  const float* proj_b = (const float*)d_in[9];
  float* out = (float*)d_out;

  char* ws = (char*)d_ws;
  unsigned short* xb = (unsigned short*)(ws + 0);          // 3,145,728 B
  unsigned short* qwb = (unsigned short*)(ws + 3145728);   //   294,912 B
  unsigned short* kvwb = (unsigned short*)(ws + 3440640);  //   589,824 B
  unsigned short* pwb = (unsigned short*)(ws + 4030464);   //   294,912 B
  unsigned short* Qs = (unsigned short*)(ws + 4325376);    // 3,145,728 B
  unsigned short* Kn = (unsigned short*)(ws + 7471104);    // 3,145,728 B
  unsigned short* VT = (unsigned short*)(ws + 10616832);   // 3,145,728 B
  unsigned short* ao = (unsigned short*)(ws + 13762560);   // 3,145,728 B
  float* bias2 = (float*)(ws + 16908288);                  //    98,304 B -> 17 MB

  prep_kernel<<<1068, 256, 0, stream>>>(x, q_w, kv_w, proj_w, pos_bias, xb, qwb,
                                        kvwb, pwb, bias2);
  gemm_qkv_norm_kernel<<<dim3(64, NH), 256, 0, stream>>>(xb, qwb, kvwb, q_b, kv_b,
                                                         qe, temp, Qs, Kn, VT);
  attn_kernel<<<768, 128, 0, stream>>>(Qs, Kn, VT, bias2, ao);
  proj_kernel<<<dim3(64, 12), 256, 0, stream>>>(ao, pwb, proj_b, out);
}

// Round 5
// 127.224 us; speedup vs baseline: 1.0260x; 1.0260x over previous
//
#include <hip/hip_runtime.h>

#define LOG2E 1.4426950408889634f

typedef __bf16 bf16x8 __attribute__((ext_vector_type(8)));
typedef short s16x4 __attribute__((ext_vector_type(4)));
typedef float f32x4 __attribute__((ext_vector_type(4)));

#define BB 2
#define NN 2048
#define CC 384
#define NH 12
#define HD 32
#define MROWS (BB * NN)   /* 4096 */

__device__ __forceinline__ unsigned short f2bf(float f) {
  __bf16 h = (__bf16)f;
  return __builtin_bit_cast(unsigned short, h);
}

__device__ __forceinline__ bf16x8 ldg_bf8(const unsigned short* p) {
  uint4 v = *reinterpret_cast<const uint4*>(p);
  return __builtin_bit_cast(bf16x8, v);
}

// fast 2^x: raw v_exp_f32 (args here are bounded ~±48, no denorm fixup needed)
__device__ __forceinline__ float fexp2(float x) {
#if __has_builtin(__builtin_amdgcn_exp2f)
  return __builtin_amdgcn_exp2f(x);
#else
  return exp2f(x);
#endif
}

// pack 4 floats -> 4 bf16 via v_cvt_pk_bf16_f32 when available
__device__ __forceinline__ s16x4 pack_bf4(float a, float b, float c, float d) {
#if __has_builtin(__builtin_amdgcn_cvt_pk_bf16_f32)
  auto lo = __builtin_amdgcn_cvt_pk_bf16_f32(a, b);
  auto hi = __builtin_amdgcn_cvt_pk_bf16_f32(c, d);
  uint2 u = {__builtin_bit_cast(unsigned int, lo),
             __builtin_bit_cast(unsigned int, hi)};
  return __builtin_bit_cast(s16x4, u);
#else
  s16x4 r = {(short)f2bf(a), (short)f2bf(b), (short)f2bf(c), (short)f2bf(d)};
  return r;
#endif
}

// async global->LDS DMA, 16B per lane; LDS dest = wave-uniform base + lane*16
typedef __attribute__((address_space(1))) const void gas_void;
typedef __attribute__((address_space(3))) void las_void;
__device__ __forceinline__ void gload_lds16(const void* g, void* l) {
  __builtin_amdgcn_global_load_lds((gas_void*)(unsigned long long)g,
                                   (las_void*)(unsigned long long)l, 16, 0, 0);
}

__device__ __forceinline__ f32x4 mfma32(bf16x8 a, bf16x8 b, f32x4 c) {
  return __builtin_amdgcn_mfma_f32_16x16x32_bf16(a, b, c, 0, 0, 0);
}

// 16x16x16 bf16 MFMA (A,B = 4 bf16/lane: X[m|n=lane&15][k=(lane>>4)*4+j];
// C/D: row=(lane>>4)*4+r, col=lane&15). Host pass must not see the builtin.
__device__ __forceinline__ f32x4 mfma16(s16x4 a, s16x4 b, f32x4 c) {
#if defined(__HIP_DEVICE_COMPILE__)
#if __has_builtin(__builtin_amdgcn_mfma_f32_16x16x16bf16_1k)
  return __builtin_amdgcn_mfma_f32_16x16x16bf16_1k(a, b, c, 0, 0, 0);
#else
  asm volatile("v_mfma_f32_16x16x16_bf16 %0, %1, %2, %0"
               : "+v"(c) : "v"(a), "v"(b));
  return c;
#endif
#else
  return c;  // host type-check stub
#endif
}

// ------- prep: fp32->bf16 casts, 8 elems/thread (G13 vectorized) -------------
// Segments (elems): x 1572864 | q_w 147456 | kv_w 294912 | proj_w 147456 |
// pos_bias 24576. Total 2187264 = 1068 blocks * 256 thr * 8.
__global__ __launch_bounds__(256) void prep_kernel(
    const float* __restrict__ x, const float* __restrict__ q_w,
    const float* __restrict__ kv_w, const float* __restrict__ proj_w,
    const float* __restrict__ pos_bias, unsigned short* __restrict__ xb,
    unsigned short* __restrict__ qwb, unsigned short* __restrict__ kvwb,
    unsigned short* __restrict__ pwb, float* __restrict__ bias2) {
  long i = (long)(blockIdx.x * 256 + threadIdx.x) * 8;
  auto cast8 = [&](const float* s, unsigned short* d, long off) {
    float4 a = *reinterpret_cast<const float4*>(s + off);
    float4 b = *reinterpret_cast<const float4*>(s + off + 4);
    s16x4 lo = pack_bf4(a.x, a.y, a.z, a.w);
    s16x4 hi = pack_bf4(b.x, b.y, b.z, b.w);
    uint2 l = __builtin_bit_cast(uint2, lo), h = __builtin_bit_cast(uint2, hi);
    uint4 o = {l.x, l.y, h.x, h.y};
    *reinterpret_cast<uint4*>(d + off) = o;
  };
  if (i < 1572864) { cast8(x, xb, i); return; }
  i -= 1572864;
  if (i < 147456) { cast8(q_w, qwb, i); return; }
  i -= 147456;
  if (i < 294912) { cast8(kv_w, kvwb, i); return; }
  i -= 294912;
  if (i < 147456) { cast8(proj_w, pwb, i); return; }
  i -= 147456;
  float4 a = *reinterpret_cast<const float4*>(pos_bias + i);
  float4 b = *reinterpret_cast<const float4*>(pos_bias + i + 4);
  a.x *= LOG2E; a.y *= LOG2E; a.z *= LOG2E; a.w *= LOG2E;
  b.x *= LOG2E; b.y *= LOG2E; b.z *= LOG2E; b.w *= LOG2E;
  *reinterpret_cast<float4*>(bias2 + i) = a;
  *reinterpret_cast<float4*>(bias2 + i + 4) = b;
}

// ------- fused QKV GEMM + l2norm, LDS-staged (m97 structure + T2 swizzle) ----
// Grid (64, NH). Block tile 64M x 96N (head h: q|k|v 32-col slices), BK=64.
// LDS tiles are row-major [row][8 x 16B]; slot column XOR-swizzled by (row&7)
// via pre-permuted GLOBAL source (linear DMA dest, rule #21) so the fragment
// ds_read_b128 spreads 16 lanes over 8 bank-groups instead of 1.
__global__ __launch_bounds__(256, 4) void gemm_qkv_norm_kernel(
    const unsigned short* __restrict__ xb, const unsigned short* __restrict__ qwb,
    const unsigned short* __restrict__ kvwb, const float* __restrict__ q_b,
    const float* __restrict__ kv_b, const float* __restrict__ qe,
    const float* __restrict__ temperature, unsigned short* __restrict__ Qs,
    unsigned short* __restrict__ Kn, unsigned short* __restrict__ VT) {
  __shared__ alignas(16) char smem[2][20480];
  int wave = threadIdx.x >> 6, lane = threadIdx.x & 63;
  int c = lane & 15, quad = lane >> 4;
  int h = blockIdx.y;
  int m0b = blockIdx.x * 64;
  int cid = wave * 64 + lane;

  auto stage = [&](int buf, int kk) {
    char* base = smem[buf];
#pragma unroll
    for (int j = 0; j < 2; ++j) {  // A: 512 chunks (64 rows x 128B)
      int chunk = j * 256 + cid;
      int row = chunk >> 3, e = chunk & 7;
      gload_lds16(xb + (long)(m0b + row) * CC + kk + (e ^ (row & 7)) * 8,
                  base + j * 4096 + wave * 1024);
    }
#pragma unroll
    for (int j = 0; j < 3; ++j) {  // B: 768 chunks (96 rows x 128B)
      int chunk = j * 256 + cid;
      int row = chunk >> 3, e = chunk & 7;
      const unsigned short* src;
      if (row < 32)      src = qwb + (long)(h * 32 + row) * CC;
      else if (row < 64) src = kvwb + (long)(h * 32 + (row - 32)) * CC;
      else               src = kvwb + (long)(CC + h * 32 + (row - 64)) * CC;
      gload_lds16(src + kk + (e ^ (row & 7)) * 8,
                  base + 8192 + j * 4096 + wave * 1024);
    }
  };

  f32x4 acc[6] = {};
  auto compute = [&](int buf) {
    const char* base = smem[buf];
#pragma unroll
    for (int kh = 0; kh < 2; ++kh) {
      int sa = ((kh * 4 + quad) ^ (c & 7)) * 16;  // swizzled slot
      bf16x8 a = *(const bf16x8*)(base + (wave * 16 + c) * 128 + sa);
#pragma unroll
      for (int t = 0; t < 6; ++t) {
        bf16x8 b = *(const bf16x8*)(base + 8192 + (t * 16 + c) * 128 + sa);
        acc[t] = mfma32(a, b, acc[t]);
      }
    }
  };

  stage(0, 0);
#pragma unroll 1
  for (int s = 0; s < 6; ++s) {
    __syncthreads();
    if (s < 5) stage((s + 1) & 1, (s + 1) * 64);
    compute(s & 1);
  }

  // epilogue: bias + l2norm(q,k) + qe/scale + stores
  int m0 = m0b + wave * 16;
  float qb0 = q_b[h * 32 + c], qb1 = q_b[h * 32 + 16 + c];
  float kb0 = kv_b[h * 32 + c], kb1 = kv_b[h * 32 + 16 + c];
  float vb0 = kv_b[CC + h * 32 + c], vb1 = kv_b[CC + h * 32 + 16 + c];
  float qe0 = qe[h * HD + c], qe1 = qe[h * HD + 16 + c];
  float sc = log1pf(expf(temperature[h])) * 11.0f;  // softplus * log2(N)
  int b = m0 >> 11;
  int nb = (m0 & 2047) + quad * 4;
  int pair = b * NH + h;
  unsigned short* qsb = Qs + ((long)pair * NN + nb) * HD;
  unsigned short* knb = Kn + ((long)pair * NN + nb) * HD;
  ushort4 vp0, vp1;
#pragma unroll
  for (int r = 0; r < 4; ++r) {
    float q0 = acc[0][r] + qb0, q1 = acc[1][r] + qb1;
    float k0 = acc[2][r] + kb0, k1 = acc[3][r] + kb1;
    float v0 = acc[4][r] + vb0, v1 = acc[5][r] + vb1;
    float qs = q0 * q0 + q1 * q1, ks = k0 * k0 + k1 * k1;
#pragma unroll
    for (int off = 8; off; off >>= 1) {
      qs += __shfl_xor(qs, off);
      ks += __shfl_xor(ks, off);
    }
    float qi = 1.0f / fmaxf(sqrtf(qs), 1e-12f);
    float ki = 1.0f / fmaxf(sqrtf(ks), 1e-12f);
    qsb[r * HD + c] = f2bf((q0 * qi + qe0) * sc);
    qsb[r * HD + 16 + c] = f2bf((q1 * qi + qe1) * sc);
    knb[r * HD + c] = f2bf(k0 * ki);
    knb[r * HD + 16 + c] = f2bf(k1 * ki);
    ((unsigned short*)&vp0)[r] = f2bf(v0);
    ((unsigned short*)&vp1)[r] = f2bf(v1);
  }
  *reinterpret_cast<ushort4*>(VT + ((long)pair * HD + c) * NN + nb) = vp0;
  *reinterpret_cast<ushort4*>(VT + ((long)pair * HD + 16 + c) * NN + nb) = vp1;
}

// -------- attention: S^T form, 256 thr (4 waves x 16 q-rows), full-K loop ----
// Grid 768 x 256. K-loop: 16 double-buffered 128-row steps. LDS = 2x16KB tiles
// + 8KB bias = 40,960 B; 768 blocks = 3 resident blocks/CU (12 waves/CU).
// T4 counted-vmcnt schedule: raw two-barrier iteration keeps the next tile's 4
// DMA loads in flight ACROSS the barrier (never vmcnt(0) in the main loop),
// instead of hipcc's full vmcnt(0)+lgkmcnt(0) drain per __syncthreads.
// T5: setprio(1) around the MFMA/exp compute phase (attn +4-7%, m191).
__global__ __launch_bounds__(256, 4) void attn_kernel(
    const unsigned short* __restrict__ Qs, const unsigned short* __restrict__ Kn,
    const unsigned short* __restrict__ VT, const float* __restrict__ bias2,
    unsigned short* __restrict__ ao) {
  __shared__ alignas(16) char smem[2][16384];  // [buf][K 8KB | V 8KB]
  __shared__ alignas(16) char biasl[8192];
  int wave = threadIdx.x >> 6, lane = threadIdx.x & 63;
  int c = lane & 15, quad = lane >> 4;
  int id = blockIdx.x;
  int xcd = id & 7, rr = id >> 3;
  int pair = (rr >> 5) * 8 + xcd;   // 3 pairs per XCD
  int qt = rr & 31;
  int h = pair % NH, b = pair / NH;
  const unsigned short* Qp = Qs + (long)pair * NN * HD;
  const char* Kg0 = (const char*)(Kn + (long)pair * NN * HD);
  const char* Vg0 = (const char*)(VT + (long)pair * HD * NN);
  const char* bp = (const char*)(bias2 + h * NN);
  int q0 = qt * 64 + wave * 16;
  bf16x8 qf = ldg_bf8(Qp + (long)(q0 + c) * HD + quad * 8);  // B-op of S^T
  f32x4 o0 = {}, o1 = {};  // O^T: d=quad*4+r (+16), q=c
  float rs = 0.f;

  const int koff = (c * 4 + quad) * 16;  // K within-chunk source permutation

  // stage K-rows [i*128, i*128+128) into smem[buf]; 4 loads per lane
  auto stage = [&](int buf, int i) {
    char* tb = smem[buf];
    long krow0 = (long)i * 128;
    const char* Kg = Kg0 + krow0 * (HD * 2);
    const char* Vg = Vg0 + krow0 * 2;
#pragma unroll
    for (int j = 0; j < 2; ++j) {
      int ck = wave * 2 + j;  // 0..7 K-chunks of 1KB
      gload_lds16(Kg + ck * 1024 + koff, tb + ck * 1024);
      int chunk = ck * 64 + lane;  // V: 512 x 16B chunks
      int d = chunk >> 4, e = chunk & 15;
      int es = e ^ (d & 15);  // within-row swizzle keeps source coalesced
      gload_lds16(Vg + (long)d * (NN * 2) + es * 16, tb + 8192 + ck * 1024);
    }
  };

  auto compute = [&](int buf, int i) {
    const char* kb = smem[buf] + lane * 16;  // lane-contig: conflict-free
    const char* vb = smem[buf] + 8192;
    const char* bl = biasl + i * 512 + quad * 16;
#pragma unroll
    for (int t8 = 0; t8 < 8; ++t8) {
      bf16x8 kf = *(const bf16x8*)(kb + t8 * 1024);
      f32x4 bbv = *(const f32x4*)(bl + t8 * 64);  // broadcast (free)
      f32x4 s = mfma32(kf, qf, bbv);  // S^T + bias via accumulator init
      float p0 = fexp2(s[0]);
      float p1 = fexp2(s[1]);
      float p2 = fexp2(s[2]);
      float p3 = fexp2(s[3]);
      rs += (p0 + p1) + (p2 + p3);
      s16x4 pf = pack_bf4(p0, p1, p2, p3);
      int vsw = (((t8 * 2 + (quad >> 1)) ^ c) * 16) + (quad & 1) * 8;
      s16x4 vlo = *(const s16x4*)(vb + c * 256 + vsw);
      s16x4 vhi = *(const s16x4*)(vb + (c + 16) * 256 + vsw);
      o0 = mfma16(vlo, pf, o0);
      o1 = mfma16(vhi, pf, o1);
    }
  };

  // one-time bias stage (8KB, 2KB per wave; 2 loads) + first tile (4 loads)
#pragma unroll
  for (int j = 0; j < 2; ++j)
    gload_lds16(bp + j * 4096 + wave * 1024 + lane * 16,
                biasl + j * 4096 + wave * 1024);
  stage(0, 0);

  // main loop: B1 (readers of buf^1 done) -> issue stage(i+1) -> wait for
  // stage(i)'s 4 loads only (vmcnt(4): the 4 new stay in flight) -> B2
  // (buf[i] globally ready) -> compute. Last iter drains to 0.
#pragma unroll 1
  for (int i = 0; i < 16; ++i) {
    asm volatile("s_waitcnt lgkmcnt(0)" ::: "memory");
    __builtin_amdgcn_s_barrier();                 // B1
    if (i < 15) {
      stage((i + 1) & 1, i + 1);
      asm volatile("s_waitcnt vmcnt(4)" ::: "memory");
    } else {
      asm volatile("s_waitcnt vmcnt(0)" ::: "memory");
    }
    __builtin_amdgcn_s_barrier();                 // B2
    __builtin_amdgcn_sched_barrier(0);            // rule #18: no hoisting
    __builtin_amdgcn_s_setprio(1);
    compute(i & 1, i);
    __builtin_amdgcn_s_setprio(0);
  }

  // per-lane row-sum for q=c (lanes c, c+16, c+32, c+48 hold the 4 k-quads)
  rs += __shfl_xor(rs, 16);
  rs += __shfl_xor(rs, 32);
  float inv = 1.0f / rs;
  unsigned short* op = ao + (long)(b * NN + q0 + c) * CC + h * HD + quad * 4;
  ushort4 s0, s1;
#pragma unroll
  for (int r = 0; r < 4; ++r) {
    ((unsigned short*)&s0)[r] = f2bf(o0[r] * inv);
    ((unsigned short*)&s1)[r] = f2bf(o1[r] * inv);
  }
  *reinterpret_cast<ushort4*>(op) = s0;
  *reinterpret_cast<ushort4*>(op + 16) = s1;
}

// ---------------- proj: out = ao @ proj_w^T + proj_b, LDS-staged -------------
// Grid (64, 12). Block tile 64M x 32N, BK=64 -> 768 blocks = exactly 3/CU.
// LDS (8KB+4KB)x2 = 24KB. Same T2 swizzle as gemm_qkv.
__global__ __launch_bounds__(256, 4) void proj_kernel(
    const unsigned short* __restrict__ ab, const unsigned short* __restrict__ pwb,
    const float* __restrict__ proj_b, float* __restrict__ out) {
  __shared__ alignas(16) char smem[2][12288];
  int wave = threadIdx.x >> 6, lane = threadIdx.x & 63;
  int c = lane & 15, quad = lane >> 4;
  int m0b = blockIdx.x * 64;
  int n0 = blockIdx.y * 32;
  int cid = wave * 64 + lane;

  auto stage = [&](int buf, int kk) {
    char* base = smem[buf];
#pragma unroll
    for (int j = 0; j < 2; ++j) {  // A: 512 chunks (64 rows x 128B)
      int chunk = j * 256 + cid;
      int row = chunk >> 3, e = chunk & 7;
      gload_lds16(ab + (long)(m0b + row) * CC + kk + (e ^ (row & 7)) * 8,
                  base + j * 4096 + wave * 1024);
    }
    {  // B: 256 chunks (32 rows x 128B)
      int row = cid >> 3, e = cid & 7;
      gload_lds16(pwb + (long)(n0 + row) * CC + kk + (e ^ (row & 7)) * 8,
                  base + 8192 + wave * 1024);
    }
  };

  f32x4 acc[2] = {};
  auto compute = [&](int buf) {
    const char* base = smem[buf];
#pragma unroll
    for (int kh = 0; kh < 2; ++kh) {
      int sa = ((kh * 4 + quad) ^ (c & 7)) * 16;  // swizzled slot
      bf16x8 a = *(const bf16x8*)(base + (wave * 16 + c) * 128 + sa);
#pragma unroll
      for (int t = 0; t < 2; ++t) {
        bf16x8 b = *(const bf16x8*)(base + 8192 + (t * 16 + c) * 128 + sa);
        acc[t] = mfma32(a, b, acc[t]);
      }
    }
  };

  stage(0, 0);
#pragma unroll 1
  for (int s = 0; s < 6; ++s) {
    __syncthreads();
    if (s < 5) stage((s + 1) & 1, (s + 1) * 64);
    compute(s & 1);
  }

  int m0 = m0b + wave * 16;
#pragma unroll
  for (int t = 0; t < 2; ++t) {
    int o = n0 + t * 16 + c;
    float bv = proj_b[o];
#pragma unroll
    for (int r = 0; r < 4; ++r) {
      out[(long)(m0 + quad * 4 + r) * CC + o] = acc[t][r] + bv;
    }
  }
}

extern "C" void kernel_launch(void* const* d_in, const int* in_sizes, int n_in,
                              void* d_out, int out_size, void* d_ws, size_t ws_size,
                              hipStream_t stream) {
  const float* x = (const float*)d_in[0];
  const float* q_w = (const float*)d_in[1];
  const float* q_b = (const float*)d_in[2];
  const float* kv_w = (const float*)d_in[3];
  const float* kv_b = (const float*)d_in[4];
  const float* qe = (const float*)d_in[5];
  const float* temp = (const float*)d_in[6];
  const float* pos_bias = (const float*)d_in[7];
  const float* proj_w = (const float*)d_in[8];
  const float* proj_b = (const float*)d_in[9];
  float* out = (float*)d_out;

  char* ws = (char*)d_ws;
  unsigned short* xb = (unsigned short*)(ws + 0);          // 3,145,728 B
  unsigned short* qwb = (unsigned short*)(ws + 3145728);   //   294,912 B
  unsigned short* kvwb = (unsigned short*)(ws + 3440640);  //   589,824 B
  unsigned short* pwb = (unsigned short*)(ws + 4030464);   //   294,912 B
  unsigned short* Qs = (unsigned short*)(ws + 4325376);    // 3,145,728 B
  unsigned short* Kn = (unsigned short*)(ws + 7471104);    // 3,145,728 B
  unsigned short* VT = (unsigned short*)(ws + 10616832);   // 3,145,728 B
  unsigned short* ao = (unsigned short*)(ws + 13762560);   // 3,145,728 B
  float* bias2 = (float*)(ws + 16908288);                  //    98,304 B -> 17 MB

  prep_kernel<<<1068, 256, 0, stream>>>(x, q_w, kv_w, proj_w, pos_bias, xb, qwb,
                                        kvwb, pwb, bias2);
  gemm_qkv_norm_kernel<<<dim3(64, NH), 256, 0, stream>>>(xb, qwb, kvwb, q_b, kv_b,
                                                         qe, temp, Qs, Kn, VT);
  attn_kernel<<<768, 256, 0, stream>>>(Qs, Kn, VT, bias2, ao);
  proj_kernel<<<dim3(64, 12), 256, 0, stream>>>(ao, pwb, proj_b, out);
}

// Round 6
// 124.688 us; speedup vs baseline: 1.0468x; 1.0203x over previous
//
#include <hip/hip_runtime.h>

#define LOG2E 1.4426950408889634f

typedef __bf16 bf16x8 __attribute__((ext_vector_type(8)));
typedef short s16x4 __attribute__((ext_vector_type(4)));
typedef float f32x4 __attribute__((ext_vector_type(4)));

#define BB 2
#define NN 2048
#define CC 384
#define NH 12
#define HD 32
#define MROWS (BB * NN)   /* 4096 */

__device__ __forceinline__ unsigned short f2bf(float f) {
  __bf16 h = (__bf16)f;
  return __builtin_bit_cast(unsigned short, h);
}

__device__ __forceinline__ bf16x8 ldg_bf8(const unsigned short* p) {
  uint4 v = *reinterpret_cast<const uint4*>(p);
  return __builtin_bit_cast(bf16x8, v);
}

// fast 2^x: raw v_exp_f32 (args here are bounded ~±48, no denorm fixup needed)
__device__ __forceinline__ float fexp2(float x) {
#if __has_builtin(__builtin_amdgcn_exp2f)
  return __builtin_amdgcn_exp2f(x);
#else
  return exp2f(x);
#endif
}

// pack 4 floats -> 4 bf16 via v_cvt_pk_bf16_f32 when available
__device__ __forceinline__ s16x4 pack_bf4(float a, float b, float c, float d) {
#if __has_builtin(__builtin_amdgcn_cvt_pk_bf16_f32)
  auto lo = __builtin_amdgcn_cvt_pk_bf16_f32(a, b);
  auto hi = __builtin_amdgcn_cvt_pk_bf16_f32(c, d);
  uint2 u = {__builtin_bit_cast(unsigned int, lo),
             __builtin_bit_cast(unsigned int, hi)};
  return __builtin_bit_cast(s16x4, u);
#else
  s16x4 r = {(short)f2bf(a), (short)f2bf(b), (short)f2bf(c), (short)f2bf(d)};
  return r;
#endif
}

// async global->LDS DMA, 16B per lane; LDS dest = wave-uniform base + lane*16
typedef __attribute__((address_space(1))) const void gas_void;
typedef __attribute__((address_space(3))) void las_void;
__device__ __forceinline__ void gload_lds16(const void* g, void* l) {
  __builtin_amdgcn_global_load_lds((gas_void*)(unsigned long long)g,
                                   (las_void*)(unsigned long long)l, 16, 0, 0);
}

__device__ __forceinline__ f32x4 mfma32(bf16x8 a, bf16x8 b, f32x4 c) {
  return __builtin_amdgcn_mfma_f32_16x16x32_bf16(a, b, c, 0, 0, 0);
}

// 16x16x16 bf16 MFMA (A,B = 4 bf16/lane: X[m|n=lane&15][k=(lane>>4)*4+j];
// C/D: row=(lane>>4)*4+r, col=lane&15). Host pass must not see the builtin.
__device__ __forceinline__ f32x4 mfma16(s16x4 a, s16x4 b, f32x4 c) {
#if defined(__HIP_DEVICE_COMPILE__)
#if __has_builtin(__builtin_amdgcn_mfma_f32_16x16x16bf16_1k)
  return __builtin_amdgcn_mfma_f32_16x16x16bf16_1k(a, b, c, 0, 0, 0);
#else
  asm volatile("v_mfma_f32_16x16x16_bf16 %0, %1, %2, %0"
               : "+v"(c) : "v"(a), "v"(b));
  return c;
#endif
#else
  return c;  // host type-check stub
#endif
}

// ------- prep: fp32->bf16 casts, 8 elems/thread (G13 vectorized) -------------
// Segments (elems): x 1572864 | q_w 147456 | kv_w 294912 | proj_w 147456 |
// pos_bias 24576. Total 2187264 = 1068 blocks * 256 thr * 8.
__global__ __launch_bounds__(256) void prep_kernel(
    const float* __restrict__ x, const float* __restrict__ q_w,
    const float* __restrict__ kv_w, const float* __restrict__ proj_w,
    const float* __restrict__ pos_bias, unsigned short* __restrict__ xb,
    unsigned short* __restrict__ qwb, unsigned short* __restrict__ kvwb,
    unsigned short* __restrict__ pwb, float* __restrict__ bias2) {
  long i = (long)(blockIdx.x * 256 + threadIdx.x) * 8;
  auto cast8 = [&](const float* s, unsigned short* d, long off) {
    float4 a = *reinterpret_cast<const float4*>(s + off);
    float4 b = *reinterpret_cast<const float4*>(s + off + 4);
    s16x4 lo = pack_bf4(a.x, a.y, a.z, a.w);
    s16x4 hi = pack_bf4(b.x, b.y, b.z, b.w);
    uint2 l = __builtin_bit_cast(uint2, lo), h = __builtin_bit_cast(uint2, hi);
    uint4 o = {l.x, l.y, h.x, h.y};
    *reinterpret_cast<uint4*>(d + off) = o;
  };
  if (i < 1572864) { cast8(x, xb, i); return; }
  i -= 1572864;
  if (i < 147456) { cast8(q_w, qwb, i); return; }
  i -= 147456;
  if (i < 294912) { cast8(kv_w, kvwb, i); return; }
  i -= 294912;
  if (i < 147456) { cast8(proj_w, pwb, i); return; }
  i -= 147456;
  float4 a = *reinterpret_cast<const float4*>(pos_bias + i);
  float4 b = *reinterpret_cast<const float4*>(pos_bias + i + 4);
  a.x *= LOG2E; a.y *= LOG2E; a.z *= LOG2E; a.w *= LOG2E;
  b.x *= LOG2E; b.y *= LOG2E; b.z *= LOG2E; b.w *= LOG2E;
  *reinterpret_cast<float4*>(bias2 + i) = a;
  *reinterpret_cast<float4*>(bias2 + i + 4) = b;
}

// ------- fused QKV GEMM + l2norm, LDS-staged (m97 structure + T2 swizzle) ----
// Grid (64, NH). Block tile 64M x 96N (head h: q|k|v 32-col slices), BK=64.
__global__ __launch_bounds__(256, 4) void gemm_qkv_norm_kernel(
    const unsigned short* __restrict__ xb, const unsigned short* __restrict__ qwb,
    const unsigned short* __restrict__ kvwb, const float* __restrict__ q_b,
    const float* __restrict__ kv_b, const float* __restrict__ qe,
    const float* __restrict__ temperature, unsigned short* __restrict__ Qs,
    unsigned short* __restrict__ Kn, unsigned short* __restrict__ VT) {
  __shared__ alignas(16) char smem[2][20480];
  int wave = threadIdx.x >> 6, lane = threadIdx.x & 63;
  int c = lane & 15, quad = lane >> 4;
  int h = blockIdx.y;
  int m0b = blockIdx.x * 64;
  int cid = wave * 64 + lane;

  auto stage = [&](int buf, int kk) {
    char* base = smem[buf];
#pragma unroll
    for (int j = 0; j < 2; ++j) {  // A: 512 chunks (64 rows x 128B)
      int chunk = j * 256 + cid;
      int row = chunk >> 3, e = chunk & 7;
      gload_lds16(xb + (long)(m0b + row) * CC + kk + (e ^ (row & 7)) * 8,
                  base + j * 4096 + wave * 1024);
    }
#pragma unroll
    for (int j = 0; j < 3; ++j) {  // B: 768 chunks (96 rows x 128B)
      int chunk = j * 256 + cid;
      int row = chunk >> 3, e = chunk & 7;
      const unsigned short* src;
      if (row < 32)      src = qwb + (long)(h * 32 + row) * CC;
      else if (row < 64) src = kvwb + (long)(h * 32 + (row - 32)) * CC;
      else               src = kvwb + (long)(CC + h * 32 + (row - 64)) * CC;
      gload_lds16(src + kk + (e ^ (row & 7)) * 8,
                  base + 8192 + j * 4096 + wave * 1024);
    }
  };

  f32x4 acc[6] = {};
  auto compute = [&](int buf) {
    const char* base = smem[buf];
#pragma unroll
    for (int kh = 0; kh < 2; ++kh) {
      int sa = ((kh * 4 + quad) ^ (c & 7)) * 16;  // swizzled slot
      bf16x8 a = *(const bf16x8*)(base + (wave * 16 + c) * 128 + sa);
#pragma unroll
      for (int t = 0; t < 6; ++t) {
        bf16x8 b = *(const bf16x8*)(base + 8192 + (t * 16 + c) * 128 + sa);
        acc[t] = mfma32(a, b, acc[t]);
      }
    }
  };

  stage(0, 0);
#pragma unroll 1
  for (int s = 0; s < 6; ++s) {
    __syncthreads();
    if (s < 5) stage((s + 1) & 1, (s + 1) * 64);
    compute(s & 1);
  }

  // epilogue: bias + l2norm(q,k) + qe/scale + stores
  int m0 = m0b + wave * 16;
  float qb0 = q_b[h * 32 + c], qb1 = q_b[h * 32 + 16 + c];
  float kb0 = kv_b[h * 32 + c], kb1 = kv_b[h * 32 + 16 + c];
  float vb0 = kv_b[CC + h * 32 + c], vb1 = kv_b[CC + h * 32 + 16 + c];
  float qe0 = qe[h * HD + c], qe1 = qe[h * HD + 16 + c];
  float sc = log1pf(expf(temperature[h])) * 11.0f;  // softplus * log2(N)
  int b = m0 >> 11;
  int nb = (m0 & 2047) + quad * 4;
  int pair = b * NH + h;
  unsigned short* qsb = Qs + ((long)pair * NN + nb) * HD;
  unsigned short* knb = Kn + ((long)pair * NN + nb) * HD;
  ushort4 vp0, vp1;
#pragma unroll
  for (int r = 0; r < 4; ++r) {
    float q0 = acc[0][r] + qb0, q1 = acc[1][r] + qb1;
    float k0 = acc[2][r] + kb0, k1 = acc[3][r] + kb1;
    float v0 = acc[4][r] + vb0, v1 = acc[5][r] + vb1;
    float qs = q0 * q0 + q1 * q1, ks = k0 * k0 + k1 * k1;
#pragma unroll
    for (int off = 8; off; off >>= 1) {
      qs += __shfl_xor(qs, off);
      ks += __shfl_xor(ks, off);
    }
    float qi = 1.0f / fmaxf(sqrtf(qs), 1e-12f);
    float ki = 1.0f / fmaxf(sqrtf(ks), 1e-12f);
    qsb[r * HD + c] = f2bf((q0 * qi + qe0) * sc);
    qsb[r * HD + 16 + c] = f2bf((q1 * qi + qe1) * sc);
    knb[r * HD + c] = f2bf(k0 * ki);
    knb[r * HD + 16 + c] = f2bf(k1 * ki);
    ((unsigned short*)&vp0)[r] = f2bf(v0);
    ((unsigned short*)&vp1)[r] = f2bf(v1);
  }
  *reinterpret_cast<ushort4*>(VT + ((long)pair * HD + c) * NN + nb) = vp0;
  *reinterpret_cast<ushort4*>(VT + ((long)pair * HD + 16 + c) * NN + nb) = vp1;
}

// -------- attention: K-SPLIT across waves, barrier-free main loop ------------
// Grid 768 x 256. Block = 64 q-rows (4 frags) x full K. Wave w owns PRIVATE
// k-range [w*512,(w+1)*512), loops 16 tiles of KVBLK=32, double-buffered in
// wave-private LDS (no __syncthreads in main loop; per-wave vmcnt/lgkmcnt).
// Every kf/vlo/vhi LDS read feeds FOUR q-fragments -> LDS-pipe cost per score
// is 1/4 of the old all-waves-read-all layout (the measured bottleneck).
// Bias read once per t8 serves all 4 frags. End: 2 barriers, cross-wave
// combine of (O, rs) partials through LDS (static reg indices only).
// LDS: 4 waves x 8KB dbuf + 8KB bias = 40,960 B -> 3 blocks/CU, zero tail.
__global__ __launch_bounds__(256, 3) void attn_kernel(
    const unsigned short* __restrict__ Qs, const unsigned short* __restrict__ Kn,
    const unsigned short* __restrict__ VT, const float* __restrict__ bias2,
    unsigned short* __restrict__ ao) {
  __shared__ alignas(16) char smem[40960];  // [w*8192: dbuf (K2K|V2K)x2][32768: bias 8K]
  int wave = threadIdx.x >> 6, lane = threadIdx.x & 63;
  int c = lane & 15, quad = lane >> 4;
  int id = blockIdx.x;
  int xcd = id & 7, rr = id >> 3;
  int pair = (rr >> 5) * 8 + xcd;   // 3 pairs per XCD
  int qt = rr & 31;
  int h = pair % NH, b = pair / NH;
  const unsigned short* Qp = Qs + (long)pair * NN * HD;
  const char* Kg0 = (const char*)(Kn + (long)pair * NN * HD) + wave * 32768;
  const char* Vg0 = (const char*)(VT + (long)pair * HD * NN) + wave * 1024;
  const char* bp = (const char*)(bias2 + h * NN);
  int q0 = qt * 64;
  bf16x8 qf0 = ldg_bf8(Qp + (long)(q0 + c) * HD + quad * 8);
  bf16x8 qf1 = ldg_bf8(Qp + (long)(q0 + 16 + c) * HD + quad * 8);
  bf16x8 qf2 = ldg_bf8(Qp + (long)(q0 + 32 + c) * HD + quad * 8);
  bf16x8 qf3 = ldg_bf8(Qp + (long)(q0 + 48 + c) * HD + quad * 8);
  f32x4 o00 = {}, o10 = {}, o01 = {}, o11 = {};
  f32x4 o02 = {}, o12 = {}, o03 = {}, o13 = {};
  float rs0 = 0.f, rs1 = 0.f, rs2 = 0.f, rs3 = 0.f;

  char* sw = smem + wave * 8192;              // private dbuf
  char* biasl = smem + 32768;
  const int koff = (c * 4 + quad) * 16;       // K within-chunk source perm
  int vd = lane >> 2, ve = lane & 3;          // V chunk: d=j*16+vd, e=ve
  int ves = ve ^ (vd & 3);                    // source swizzle (involution)

  // stage tile i (32 krows) of this wave's range into private buf
  auto stage = [&](int buf, int i) {
    char* tb = sw + buf * 4096;
    const char* Kg = Kg0 + i * 2048;          // 32 rows x 64 B
    const char* Vg = Vg0 + i * 64;            // 32 cols x 2 B
#pragma unroll
    for (int j = 0; j < 2; ++j) {
      gload_lds16(Kg + j * 1024 + koff, tb + j * 1024);
      gload_lds16(Vg + (long)(j * 16 + vd) * (NN * 2) + ves * 16,
                  tb + 2048 + j * 1024);
    }
  };

#define FRAG_STEP(QF, O0, O1, RS)              \
  {                                            \
    f32x4 s = mfma32(kf, QF, bbv);             \
    float p0 = fexp2(s[0]), p1 = fexp2(s[1]);  \
    float p2 = fexp2(s[2]), p3 = fexp2(s[3]);  \
    RS += (p0 + p1) + (p2 + p3);               \
    s16x4 pf = pack_bf4(p0, p1, p2, p3);       \
    O0 = mfma16(vlo, pf, O0);                  \
    O1 = mfma16(vhi, pf, O1);                  \
  }

  auto compute = [&](int buf, int i) {
    const char* kb = sw + buf * 4096 + lane * 16;
    const char* vb = sw + buf * 4096 + 2048;
    const char* bl = biasl + wave * 2048 + i * 128 + quad * 16;
#pragma unroll
    for (int t8 = 0; t8 < 2; ++t8) {
      bf16x8 kf = *(const bf16x8*)(kb + t8 * 1024);
      f32x4 bbv = *(const f32x4*)(bl + t8 * 64);  // 4-addr broadcast (free)
      int sl = ((t8 * 2 + (quad >> 1)) ^ (c & 3)) * 16 + (quad & 1) * 8;
      s16x4 vlo = *(const s16x4*)(vb + c * 64 + sl);
      s16x4 vhi = *(const s16x4*)(vb + 1024 + c * 64 + sl);
      FRAG_STEP(qf0, o00, o10, rs0)
      FRAG_STEP(qf1, o01, o11, rs1)
      FRAG_STEP(qf2, o02, o12, rs2)
      FRAG_STEP(qf3, o03, o13, rs3)
    }
  };
#undef FRAG_STEP

  // prologue: bias (shared, 2 loads/lane) + first private tile; one full drain
#pragma unroll
  for (int j = 0; j < 2; ++j)
    gload_lds16(bp + j * 4096 + wave * 1024 + lane * 16,
                biasl + j * 4096 + wave * 1024);
  stage(0, 0);
  __syncthreads();

  // barrier-free main loop: issue next private tile, wait only for current
  // (vmcnt(4): next tile's 4 DMAs stay in flight), compute.
#pragma unroll 1
  for (int i = 0; i < 16; ++i) {
    asm volatile("s_waitcnt lgkmcnt(0)" ::: "memory");  // prior buf reads done
    if (i < 15) {
      stage((i + 1) & 1, i + 1);
      asm volatile("s_waitcnt vmcnt(4)" ::: "memory");
    } else {
      asm volatile("s_waitcnt vmcnt(0)" ::: "memory");
    }
    __builtin_amdgcn_sched_barrier(0);  // rule #18: no ds_read hoist past wait
    compute(i & 1, i);
  }

  // ---- cross-wave combine: comb[frag][w][comp][lane] f32, 36,864 B ----------
  __syncthreads();
  float* comb = (float*)smem;
#define PUT(F, O0, O1, RS)                                          \
  {                                                                 \
    float* p = comb + ((F * 4 + wave) * 9) * 64 + lane;             \
    p[0] = O0[0]; p[64] = O0[1]; p[128] = O0[2]; p[192] = O0[3];    \
    p[256] = O1[0]; p[320] = O1[1]; p[384] = O1[2]; p[448] = O1[3]; \
    p[512] = RS;                                                    \
  }
  PUT(0, o00, o10, rs0)
  PUT(1, o01, o11, rs1)
  PUT(2, o02, o12, rs2)
  PUT(3, o03, o13, rs3)
#undef PUT
  __syncthreads();
  // wave w finalizes frag w (q-rows q0 + w*16 .. +16)
  f32x4 A0 = {}, A1 = {};
  float AR = 0.f;
#pragma unroll
  for (int w2 = 0; w2 < 4; ++w2) {
    const float* p = comb + ((wave * 4 + w2) * 9) * 64 + lane;
    A0[0] += p[0]; A0[1] += p[64]; A0[2] += p[128]; A0[3] += p[192];
    A1[0] += p[256]; A1[1] += p[320]; A1[2] += p[384]; A1[3] += p[448];
    AR += p[512];
  }
  AR += __shfl_xor(AR, 16);
  AR += __shfl_xor(AR, 32);
  float inv = 1.0f / AR;
  int qr = q0 + wave * 16 + c;
  unsigned short* op = ao + (long)(b * NN + qr) * CC + h * HD + quad * 4;
  ushort4 s0, s1;
#pragma unroll
  for (int r = 0; r < 4; ++r) {
    ((unsigned short*)&s0)[r] = f2bf(A0[r] * inv);
    ((unsigned short*)&s1)[r] = f2bf(A1[r] * inv);
  }
  *reinterpret_cast<ushort4*>(op) = s0;
  *reinterpret_cast<ushort4*>(op + 16) = s1;
}

// ---------------- proj: out = ao @ proj_w^T + proj_b, LDS-staged -------------
// Grid (64, 12). Block tile 64M x 32N, BK=64 -> 768 blocks = exactly 3/CU.
__global__ __launch_bounds__(256, 4) void proj_kernel(
    const unsigned short* __restrict__ ab, const unsigned short* __restrict__ pwb,
    const float* __restrict__ proj_b, float* __restrict__ out) {
  __shared__ alignas(16) char smem[2][12288];
  int wave = threadIdx.x >> 6, lane = threadIdx.x & 63;
  int c = lane & 15, quad = lane >> 4;
  int m0b = blockIdx.x * 64;
  int n0 = blockIdx.y * 32;
  int cid = wave * 64 + lane;

  auto stage = [&](int buf, int kk) {
    char* base = smem[buf];
#pragma unroll
    for (int j = 0; j < 2; ++j) {  // A: 512 chunks (64 rows x 128B)
      int chunk = j * 256 + cid;
      int row = chunk >> 3, e = chunk & 7;
      gload_lds16(ab + (long)(m0b + row) * CC + kk + (e ^ (row & 7)) * 8,
                  base + j * 4096 + wave * 1024);
    }
    {  // B: 256 chunks (32 rows x 128B)
      int row = cid >> 3, e = cid & 7;
      gload_lds16(pwb + (long)(n0 + row) * CC + kk + (e ^ (row & 7)) * 8,
                  base + 8192 + wave * 1024);
    }
  };

  f32x4 acc[2] = {};
  auto compute = [&](int buf) {
    const char* base = smem[buf];
#pragma unroll
    for (int kh = 0; kh < 2; ++kh) {
      int sa = ((kh * 4 + quad) ^ (c & 7)) * 16;  // swizzled slot
      bf16x8 a = *(const bf16x8*)(base + (wave * 16 + c) * 128 + sa);
#pragma unroll
      for (int t = 0; t < 2; ++t) {
        bf16x8 b = *(const bf16x8*)(base + 8192 + (t * 16 + c) * 128 + sa);
        acc[t] = mfma32(a, b, acc[t]);
      }
    }
  };

  stage(0, 0);
#pragma unroll 1
  for (int s = 0; s < 6; ++s) {
    __syncthreads();
    if (s < 5) stage((s + 1) & 1, (s + 1) * 64);
    compute(s & 1);
  }

  int m0 = m0b + wave * 16;
#pragma unroll
  for (int t = 0; t < 2; ++t) {
    int o = n0 + t * 16 + c;
    float bv = proj_b[o];
#pragma unroll
    for (int r = 0; r < 4; ++r) {
      out[(long)(m0 + quad * 4 + r) * CC + o] = acc[t][r] + bv;
    }
  }
}

extern "C" void kernel_launch(void* const* d_in, const int* in_sizes, int n_in,
                              void* d_out, int out_size, void* d_ws, size_t ws_size,
                              hipStream_t stream) {
  const float* x = (const float*)d_in[0];
  const float* q_w = (const float*)d_in[1];
  const float* q_b = (const float*)d_in[2];
  const float* kv_w = (const float*)d_in[3];
  const float* kv_b = (const float*)d_in[4];
  const float* qe = (const float*)d_in[5];
  const float* temp = (const float*)d_in[6];
  const float* pos_bias = (const float*)d_in[7];
  const float* proj_w = (const float*)d_in[8];
  const float* proj_b = (const float*)d_in[9];
  float* out = (float*)d_out;

  char* ws = (char*)d_ws;
  unsigned short* xb = (unsigned short*)(ws + 0);          // 3,145,728 B
  unsigned short* qwb = (unsigned short*)(ws + 3145728);   //   294,912 B
  unsigned short* kvwb = (unsigned short*)(ws + 3440640);  //   589,824 B
  unsigned short* pwb = (unsigned short*)(ws + 4030464);   //   294,912 B
  unsigned short* Qs = (unsigned short*)(ws + 4325376);    // 3,145,728 B
  unsigned short* Kn = (unsigned short*)(ws + 7471104);    // 3,145,728 B
  unsigned short* VT = (unsigned short*)(ws + 10616832);   // 3,145,728 B
  unsigned short* ao = (unsigned short*)(ws + 13762560);   // 3,145,728 B
  float* bias2 = (float*)(ws + 16908288);                  //    98,304 B -> 17 MB

  prep_kernel<<<1068, 256, 0, stream>>>(x, q_w, kv_w, proj_w, pos_bias, xb, qwb,
                                        kvwb, pwb, bias2);
  gemm_qkv_norm_kernel<<<dim3(64, NH), 256, 0, stream>>>(xb, qwb, kvwb, q_b, kv_b,
                                                         qe, temp, Qs, Kn, VT);
  attn_kernel<<<768, 256, 0, stream>>>(Qs, Kn, VT, bias2, ao);
  proj_kernel<<<dim3(64, 12), 256, 0, stream>>>(ao, pwb, proj_b, out);
}

// Round 7
// 122.747 us; speedup vs baseline: 1.0634x; 1.0158x over previous
//
#include <hip/hip_runtime.h>

#define LOG2E 1.4426950408889634f

typedef __bf16 bf16x8 __attribute__((ext_vector_type(8)));
typedef short s16x4 __attribute__((ext_vector_type(4)));
typedef float f32x4 __attribute__((ext_vector_type(4)));

#define BB 2
#define NN 2048
#define CC 384
#define NH 12
#define HD 32
#define MROWS (BB * NN)   /* 4096 */

__device__ __forceinline__ unsigned short f2bf(float f) {
  __bf16 h = (__bf16)f;
  return __builtin_bit_cast(unsigned short, h);
}

__device__ __forceinline__ bf16x8 ldg_bf8(const unsigned short* p) {
  uint4 v = *reinterpret_cast<const uint4*>(p);
  return __builtin_bit_cast(bf16x8, v);
}

// fast 2^x: raw v_exp_f32 (args here are bounded ~±48, no denorm fixup needed)
__device__ __forceinline__ float fexp2(float x) {
#if __has_builtin(__builtin_amdgcn_exp2f)
  return __builtin_amdgcn_exp2f(x);
#else
  return exp2f(x);
#endif
}

// pack 4 floats -> 4 bf16 via v_cvt_pk_bf16_f32 when available
__device__ __forceinline__ s16x4 pack_bf4(float a, float b, float c, float d) {
#if __has_builtin(__builtin_amdgcn_cvt_pk_bf16_f32)
  auto lo = __builtin_amdgcn_cvt_pk_bf16_f32(a, b);
  auto hi = __builtin_amdgcn_cvt_pk_bf16_f32(c, d);
  uint2 u = {__builtin_bit_cast(unsigned int, lo),
             __builtin_bit_cast(unsigned int, hi)};
  return __builtin_bit_cast(s16x4, u);
#else
  s16x4 r = {(short)f2bf(a), (short)f2bf(b), (short)f2bf(c), (short)f2bf(d)};
  return r;
#endif
}

// async global->LDS DMA, 16B per lane; LDS dest = wave-uniform base + lane*16
typedef __attribute__((address_space(1))) const void gas_void;
typedef __attribute__((address_space(3))) void las_void;
__device__ __forceinline__ void gload_lds16(const void* g, void* l) {
  __builtin_amdgcn_global_load_lds((gas_void*)(unsigned long long)g,
                                   (las_void*)(unsigned long long)l, 16, 0, 0);
}

__device__ __forceinline__ f32x4 mfma32(bf16x8 a, bf16x8 b, f32x4 c) {
  return __builtin_amdgcn_mfma_f32_16x16x32_bf16(a, b, c, 0, 0, 0);
}

// 16x16x16 bf16 MFMA (A,B = 4 bf16/lane: X[m|n=lane&15][k=(lane>>4)*4+j];
// C/D: row=(lane>>4)*4+r, col=lane&15). Host pass must not see the builtin.
__device__ __forceinline__ f32x4 mfma16(s16x4 a, s16x4 b, f32x4 c) {
#if defined(__HIP_DEVICE_COMPILE__)
#if __has_builtin(__builtin_amdgcn_mfma_f32_16x16x16bf16_1k)
  return __builtin_amdgcn_mfma_f32_16x16x16bf16_1k(a, b, c, 0, 0, 0);
#else
  asm volatile("v_mfma_f32_16x16x16_bf16 %0, %1, %2, %0"
               : "+v"(c) : "v"(a), "v"(b));
  return c;
#endif
#else
  return c;  // host type-check stub
#endif
}

// ------- prep: fp32->bf16 casts, 8 elems/thread (G13 vectorized) -------------
// Segments (elems): x 1572864 | q_w 147456 | kv_w 294912 | proj_w 147456 |
// pos_bias 24576. Total 2187264 = 1068 blocks * 256 thr * 8.
__global__ __launch_bounds__(256) void prep_kernel(
    const float* __restrict__ x, const float* __restrict__ q_w,
    const float* __restrict__ kv_w, const float* __restrict__ proj_w,
    const float* __restrict__ pos_bias, unsigned short* __restrict__ xb,
    unsigned short* __restrict__ qwb, unsigned short* __restrict__ kvwb,
    unsigned short* __restrict__ pwb, float* __restrict__ bias2) {
  long i = (long)(blockIdx.x * 256 + threadIdx.x) * 8;
  auto cast8 = [&](const float* s, unsigned short* d, long off) {
    float4 a = *reinterpret_cast<const float4*>(s + off);
    float4 b = *reinterpret_cast<const float4*>(s + off + 4);
    s16x4 lo = pack_bf4(a.x, a.y, a.z, a.w);
    s16x4 hi = pack_bf4(b.x, b.y, b.z, b.w);
    uint2 l = __builtin_bit_cast(uint2, lo), h = __builtin_bit_cast(uint2, hi);
    uint4 o = {l.x, l.y, h.x, h.y};
    *reinterpret_cast<uint4*>(d + off) = o;
  };
  if (i < 1572864) { cast8(x, xb, i); return; }
  i -= 1572864;
  if (i < 147456) { cast8(q_w, qwb, i); return; }
  i -= 147456;
  if (i < 294912) { cast8(kv_w, kvwb, i); return; }
  i -= 294912;
  if (i < 147456) { cast8(proj_w, pwb, i); return; }
  i -= 147456;
  float4 a = *reinterpret_cast<const float4*>(pos_bias + i);
  float4 b = *reinterpret_cast<const float4*>(pos_bias + i + 4);
  a.x *= LOG2E; a.y *= LOG2E; a.z *= LOG2E; a.w *= LOG2E;
  b.x *= LOG2E; b.y *= LOG2E; b.z *= LOG2E; b.w *= LOG2E;
  *reinterpret_cast<float4*>(bias2 + i) = a;
  *reinterpret_cast<float4*>(bias2 + i + 4) = b;
}

// ------- fused QKV GEMM + l2norm, LDS-staged (m97 structure + T2 swizzle) ----
// Grid (64, NH). Block tile 64M x 96N (head h: q|k|v 32-col slices), BK=64.
// V output uses the BLOCKED layout VT[pair][nblk=n/32][d=32][ns=n%32] so the
// attn kernel's V tiles are contiguous 2KB blocks (one per 32 krows).
__global__ __launch_bounds__(256, 4) void gemm_qkv_norm_kernel(
    const unsigned short* __restrict__ xb, const unsigned short* __restrict__ qwb,
    const unsigned short* __restrict__ kvwb, const float* __restrict__ q_b,
    const float* __restrict__ kv_b, const float* __restrict__ qe,
    const float* __restrict__ temperature, unsigned short* __restrict__ Qs,
    unsigned short* __restrict__ Kn, unsigned short* __restrict__ VT) {
  __shared__ alignas(16) char smem[2][20480];
  int wave = threadIdx.x >> 6, lane = threadIdx.x & 63;
  int c = lane & 15, quad = lane >> 4;
  int h = blockIdx.y;
  int m0b = blockIdx.x * 64;
  int cid = wave * 64 + lane;

  auto stage = [&](int buf, int kk) {
    char* base = smem[buf];
#pragma unroll
    for (int j = 0; j < 2; ++j) {  // A: 512 chunks (64 rows x 128B)
      int chunk = j * 256 + cid;
      int row = chunk >> 3, e = chunk & 7;
      gload_lds16(xb + (long)(m0b + row) * CC + kk + (e ^ (row & 7)) * 8,
                  base + j * 4096 + wave * 1024);
    }
#pragma unroll
    for (int j = 0; j < 3; ++j) {  // B: 768 chunks (96 rows x 128B)
      int chunk = j * 256 + cid;
      int row = chunk >> 3, e = chunk & 7;
      const unsigned short* src;
      if (row < 32)      src = qwb + (long)(h * 32 + row) * CC;
      else if (row < 64) src = kvwb + (long)(h * 32 + (row - 32)) * CC;
      else               src = kvwb + (long)(CC + h * 32 + (row - 64)) * CC;
      gload_lds16(src + kk + (e ^ (row & 7)) * 8,
                  base + 8192 + j * 4096 + wave * 1024);
    }
  };

  f32x4 acc[6] = {};
  auto compute = [&](int buf) {
    const char* base = smem[buf];
#pragma unroll
    for (int kh = 0; kh < 2; ++kh) {
      int sa = ((kh * 4 + quad) ^ (c & 7)) * 16;  // swizzled slot
      bf16x8 a = *(const bf16x8*)(base + (wave * 16 + c) * 128 + sa);
#pragma unroll
      for (int t = 0; t < 6; ++t) {
        bf16x8 b = *(const bf16x8*)(base + 8192 + (t * 16 + c) * 128 + sa);
        acc[t] = mfma32(a, b, acc[t]);
      }
    }
  };

  stage(0, 0);
#pragma unroll 1
  for (int s = 0; s < 6; ++s) {
    __syncthreads();
    if (s < 5) stage((s + 1) & 1, (s + 1) * 64);
    compute(s & 1);
  }

  // epilogue: bias + l2norm(q,k) + qe/scale + stores
  int m0 = m0b + wave * 16;
  float qb0 = q_b[h * 32 + c], qb1 = q_b[h * 32 + 16 + c];
  float kb0 = kv_b[h * 32 + c], kb1 = kv_b[h * 32 + 16 + c];
  float vb0 = kv_b[CC + h * 32 + c], vb1 = kv_b[CC + h * 32 + 16 + c];
  float qe0 = qe[h * HD + c], qe1 = qe[h * HD + 16 + c];
  float sc = log1pf(expf(temperature[h])) * 11.0f;  // softplus * log2(N)
  int b = m0 >> 11;
  int nb = (m0 & 2047) + quad * 4;
  int pair = b * NH + h;
  unsigned short* qsb = Qs + ((long)pair * NN + nb) * HD;
  unsigned short* knb = Kn + ((long)pair * NN + nb) * HD;
  ushort4 vp0, vp1;
#pragma unroll
  for (int r = 0; r < 4; ++r) {
    float q0 = acc[0][r] + qb0, q1 = acc[1][r] + qb1;
    float k0 = acc[2][r] + kb0, k1 = acc[3][r] + kb1;
    float v0 = acc[4][r] + vb0, v1 = acc[5][r] + vb1;
    float qs = q0 * q0 + q1 * q1, ks = k0 * k0 + k1 * k1;
#pragma unroll
    for (int off = 8; off; off >>= 1) {
      qs += __shfl_xor(qs, off);
      ks += __shfl_xor(ks, off);
    }
    float qi = 1.0f / fmaxf(sqrtf(qs), 1e-12f);
    float ki = 1.0f / fmaxf(sqrtf(ks), 1e-12f);
    qsb[r * HD + c] = f2bf((q0 * qi + qe0) * sc);
    qsb[r * HD + 16 + c] = f2bf((q1 * qi + qe1) * sc);
    knb[r * HD + c] = f2bf(k0 * ki);
    knb[r * HD + 16 + c] = f2bf(k1 * ki);
    ((unsigned short*)&vp0)[r] = f2bf(v0);
    ((unsigned short*)&vp1)[r] = f2bf(v1);
  }
  // blocked VT store: offset(pair,d,n) = (pair*64 + n/32)*1024 + d*32 + n%32.
  // nb%4==0 so the 4 consecutive n of vp stay inside one 32-block (ushort4 ok).
  long vbo = ((long)pair * 64 + (nb >> 5)) * 1024 + (nb & 31);
  *reinterpret_cast<ushort4*>(VT + vbo + c * 32) = vp0;
  *reinterpret_cast<ushort4*>(VT + vbo + (16 + c) * 32) = vp1;
}

// -------- attention: K-SPLIT across waves, barrier-free main loop ------------
// Grid 768 x 256. Block = 64 q-rows (4 frags) x full K. Wave w owns PRIVATE
// k-range [w*512,(w+1)*512), loops 16 tiles of KVBLK=32, double-buffered in
// wave-private LDS (no __syncthreads in main loop; per-wave vmcnt/lgkmcnt).
// NEW: VT is blocked [pair][nblk][d][ns] so each V tile is a CONTIGUOUS 2KB
// block -> both V gload_lds16 per tile are contiguous 1KB reads (was 16
// scattered 64B rows at 4KB stride -> 16 cache lines/instr; that scatter's
// L2 latency exceeded the 1-tile-deep prefetch window and stalled vmcnt(4)).
// LDS: 4 waves x 8KB dbuf + 8KB bias = 40,960 B -> 3 blocks/CU, zero tail.
__global__ __launch_bounds__(256, 3) void attn_kernel(
    const unsigned short* __restrict__ Qs, const unsigned short* __restrict__ Kn,
    const unsigned short* __restrict__ VT, const float* __restrict__ bias2,
    unsigned short* __restrict__ ao) {
  __shared__ alignas(16) char smem[40960];  // [w*8192: dbuf (K2K|V2K)x2][32768: bias 8K]
  int wave = threadIdx.x >> 6, lane = threadIdx.x & 63;
  int c = lane & 15, quad = lane >> 4;
  int id = blockIdx.x;
  int xcd = id & 7, rr = id >> 3;
  int pair = (rr >> 5) * 8 + xcd;   // 3 pairs per XCD
  int qt = rr & 31;
  int h = pair % NH, b = pair / NH;
  const unsigned short* Qp = Qs + (long)pair * NN * HD;
  const char* Kg0 = (const char*)(Kn + (long)pair * NN * HD) + wave * 32768;
  // V: blocked layout; this wave's 16 tiles start at nblk = wave*16
  const char* Vg0 = (const char*)(VT) + ((long)pair * 64 + wave * 16) * 2048;
  const char* bp = (const char*)(bias2 + h * NN);
  int q0 = qt * 64;
  bf16x8 qf0 = ldg_bf8(Qp + (long)(q0 + c) * HD + quad * 8);
  bf16x8 qf1 = ldg_bf8(Qp + (long)(q0 + 16 + c) * HD + quad * 8);
  bf16x8 qf2 = ldg_bf8(Qp + (long)(q0 + 32 + c) * HD + quad * 8);
  bf16x8 qf3 = ldg_bf8(Qp + (long)(q0 + 48 + c) * HD + quad * 8);
  f32x4 o00 = {}, o10 = {}, o01 = {}, o11 = {};
  f32x4 o02 = {}, o12 = {}, o03 = {}, o13 = {};
  float rs0 = 0.f, rs1 = 0.f, rs2 = 0.f, rs3 = 0.f;

  char* sw = smem + wave * 8192;              // private dbuf
  char* biasl = smem + 32768;
  const int koff = (c * 4 + quad) * 16;       // K within-chunk source perm
  int vd = lane >> 2, ve = lane & 3;          // V unit coords within tile
  int ves = ve ^ (vd & 3);                    // source swizzle (involution)

  // stage tile i (32 krows) of this wave's range into private buf
  auto stage = [&](int buf, int i) {
    char* tb = sw + buf * 4096;
    const char* Kg = Kg0 + i * 2048;          // 32 rows x 64 B (contiguous)
    const char* Vg = Vg0 + i * 2048;          // contiguous 2KB V tile
#pragma unroll
    for (int j = 0; j < 2; ++j) {
      gload_lds16(Kg + j * 1024 + koff, tb + j * 1024);
      gload_lds16(Vg + (long)(j * 16 + vd) * 64 + ves * 16,
                  tb + 2048 + j * 1024);
    }
  };

#define FRAG_STEP(QF, O0, O1, RS)              \
  {                                            \
    f32x4 s = mfma32(kf, QF, bbv);             \
    float p0 = fexp2(s[0]), p1 = fexp2(s[1]);  \
    float p2 = fexp2(s[2]), p3 = fexp2(s[3]);  \
    RS += (p0 + p1) + (p2 + p3);               \
    s16x4 pf = pack_bf4(p0, p1, p2, p3);       \
    O0 = mfma16(vlo, pf, O0);                  \
    O1 = mfma16(vhi, pf, O1);                  \
  }

  auto compute = [&](int buf, int i) {
    const char* kb = sw + buf * 4096 + lane * 16;
    const char* vb = sw + buf * 4096 + 2048;
    const char* bl = biasl + wave * 2048 + i * 128 + quad * 16;
#pragma unroll
    for (int t8 = 0; t8 < 2; ++t8) {
      bf16x8 kf = *(const bf16x8*)(kb + t8 * 1024);
      f32x4 bbv = *(const f32x4*)(bl + t8 * 64);  // 4-addr broadcast (free)
      int sl = ((t8 * 2 + (quad >> 1)) ^ (c & 3)) * 16 + (quad & 1) * 8;
      s16x4 vlo = *(const s16x4*)(vb + c * 64 + sl);
      s16x4 vhi = *(const s16x4*)(vb + 1024 + c * 64 + sl);
      FRAG_STEP(qf0, o00, o10, rs0)
      FRAG_STEP(qf1, o01, o11, rs1)
      FRAG_STEP(qf2, o02, o12, rs2)
      FRAG_STEP(qf3, o03, o13, rs3)
    }
  };
#undef FRAG_STEP

  // prologue: bias (shared, 2 loads/lane) + first private tile; one full drain
#pragma unroll
  for (int j = 0; j < 2; ++j)
    gload_lds16(bp + j * 4096 + wave * 1024 + lane * 16,
                biasl + j * 4096 + wave * 1024);
  stage(0, 0);
  __syncthreads();

  // barrier-free main loop: issue next private tile, wait only for current
  // (vmcnt(4): next tile's 4 DMAs stay in flight), compute.
#pragma unroll 1
  for (int i = 0; i < 16; ++i) {
    asm volatile("s_waitcnt lgkmcnt(0)" ::: "memory");  // prior buf reads done
    if (i < 15) {
      stage((i + 1) & 1, i + 1);
      asm volatile("s_waitcnt vmcnt(4)" ::: "memory");
    } else {
      asm volatile("s_waitcnt vmcnt(0)" ::: "memory");
    }
    __builtin_amdgcn_sched_barrier(0);  // rule #18: no ds_read hoist past wait
    compute(i & 1, i);
  }

  // ---- cross-wave combine: comb[frag][w][comp][lane] f32, 36,864 B ----------
  __syncthreads();
  float* comb = (float*)smem;
#define PUT(F, O0, O1, RS)                                          \
  {                                                                 \
    float* p = comb + ((F * 4 + wave) * 9) * 64 + lane;             \
    p[0] = O0[0]; p[64] = O0[1]; p[128] = O0[2]; p[192] = O0[3];    \
    p[256] = O1[0]; p[320] = O1[1]; p[384] = O1[2]; p[448] = O1[3]; \
    p[512] = RS;                                                    \
  }
  PUT(0, o00, o10, rs0)
  PUT(1, o01, o11, rs1)
  PUT(2, o02, o12, rs2)
  PUT(3, o03, o13, rs3)
#undef PUT
  __syncthreads();
  // wave w finalizes frag w (q-rows q0 + w*16 .. +16)
  f32x4 A0 = {}, A1 = {};
  float AR = 0.f;
#pragma unroll
  for (int w2 = 0; w2 < 4; ++w2) {
    const float* p = comb + ((wave * 4 + w2) * 9) * 64 + lane;
    A0[0] += p[0]; A0[1] += p[64]; A0[2] += p[128]; A0[3] += p[192];
    A1[0] += p[256]; A1[1] += p[320]; A1[2] += p[384]; A1[3] += p[448];
    AR += p[512];
  }
  AR += __shfl_xor(AR, 16);
  AR += __shfl_xor(AR, 32);
  float inv = 1.0f / AR;
  int qr = q0 + wave * 16 + c;
  unsigned short* op = ao + (long)(b * NN + qr) * CC + h * HD + quad * 4;
  ushort4 s0, s1;
#pragma unroll
  for (int r = 0; r < 4; ++r) {
    ((unsigned short*)&s0)[r] = f2bf(A0[r] * inv);
    ((unsigned short*)&s1)[r] = f2bf(A1[r] * inv);
  }
  *reinterpret_cast<ushort4*>(op) = s0;
  *reinterpret_cast<ushort4*>(op + 16) = s1;
}

// ---------------- proj: out = ao @ proj_w^T + proj_b, LDS-staged -------------
// Grid (64, 12). Block tile 64M x 32N, BK=64 -> 768 blocks = exactly 3/CU.
__global__ __launch_bounds__(256, 4) void proj_kernel(
    const unsigned short* __restrict__ ab, const unsigned short* __restrict__ pwb,
    const float* __restrict__ proj_b, float* __restrict__ out) {
  __shared__ alignas(16) char smem[2][12288];
  int wave = threadIdx.x >> 6, lane = threadIdx.x & 63;
  int c = lane & 15, quad = lane >> 4;
  int m0b = blockIdx.x * 64;
  int n0 = blockIdx.y * 32;
  int cid = wave * 64 + lane;

  auto stage = [&](int buf, int kk) {
    char* base = smem[buf];
#pragma unroll
    for (int j = 0; j < 2; ++j) {  // A: 512 chunks (64 rows x 128B)
      int chunk = j * 256 + cid;
      int row = chunk >> 3, e = chunk & 7;
      gload_lds16(ab + (long)(m0b + row) * CC + kk + (e ^ (row & 7)) * 8,
                  base + j * 4096 + wave * 1024);
    }
    {  // B: 256 chunks (32 rows x 128B)
      int row = cid >> 3, e = cid & 7;
      gload_lds16(pwb + (long)(n0 + row) * CC + kk + (e ^ (row & 7)) * 8,
                  base + 8192 + wave * 1024);
    }
  };

  f32x4 acc[2] = {};
  auto compute = [&](int buf) {
    const char* base = smem[buf];
#pragma unroll
    for (int kh = 0; kh < 2; ++kh) {
      int sa = ((kh * 4 + quad) ^ (c & 7)) * 16;  // swizzled slot
      bf16x8 a = *(const bf16x8*)(base + (wave * 16 + c) * 128 + sa);
#pragma unroll
      for (int t = 0; t < 2; ++t) {
        bf16x8 b = *(const bf16x8*)(base + 8192 + (t * 16 + c) * 128 + sa);
        acc[t] = mfma32(a, b, acc[t]);
      }
    }
  };

  stage(0, 0);
#pragma unroll 1
  for (int s = 0; s < 6; ++s) {
    __syncthreads();
    if (s < 5) stage((s + 1) & 1, (s + 1) * 64);
    compute(s & 1);
  }

  int m0 = m0b + wave * 16;
#pragma unroll
  for (int t = 0; t < 2; ++t) {
    int o = n0 + t * 16 + c;
    float bv = proj_b[o];
#pragma unroll
    for (int r = 0; r < 4; ++r) {
      out[(long)(m0 + quad * 4 + r) * CC + o] = acc[t][r] + bv;
    }
  }
}

extern "C" void kernel_launch(void* const* d_in, const int* in_sizes, int n_in,
                              void* d_out, int out_size, void* d_ws, size_t ws_size,
                              hipStream_t stream) {
  const float* x = (const float*)d_in[0];
  const float* q_w = (const float*)d_in[1];
  const float* q_b = (const float*)d_in[2];
  const float* kv_w = (const float*)d_in[3];
  const float* kv_b = (const float*)d_in[4];
  const float* qe = (const float*)d_in[5];
  const float* temp = (const float*)d_in[6];
  const float* pos_bias = (const float*)d_in[7];
  const float* proj_w = (const float*)d_in[8];
  const float* proj_b = (const float*)d_in[9];
  float* out = (float*)d_out;

  char* ws = (char*)d_ws;
  unsigned short* xb = (unsigned short*)(ws + 0);          // 3,145,728 B
  unsigned short* qwb = (unsigned short*)(ws + 3145728);   //   294,912 B
  unsigned short* kvwb = (unsigned short*)(ws + 3440640);  //   589,824 B
  unsigned short* pwb = (unsigned short*)(ws + 4030464);   //   294,912 B
  unsigned short* Qs = (unsigned short*)(ws + 4325376);    // 3,145,728 B
  unsigned short* Kn = (unsigned short*)(ws + 7471104);    // 3,145,728 B
  unsigned short* VT = (unsigned short*)(ws + 10616832);   // 3,145,728 B
  unsigned short* ao = (unsigned short*)(ws + 13762560);   // 3,145,728 B
  float* bias2 = (float*)(ws + 16908288);                  //    98,304 B -> 17 MB

  prep_kernel<<<1068, 256, 0, stream>>>(x, q_w, kv_w, proj_w, pos_bias, xb, qwb,
                                        kvwb, pwb, bias2);
  gemm_qkv_norm_kernel<<<dim3(64, NH), 256, 0, stream>>>(xb, qwb, kvwb, q_b, kv_b,
                                                         qe, temp, Qs, Kn, VT);
  attn_kernel<<<768, 256, 0, stream>>>(Qs, Kn, VT, bias2, ao);
  proj_kernel<<<dim3(64, 12), 256, 0, stream>>>(ao, pwb, proj_b, out);
}

// Round 9
// 122.014 us; speedup vs baseline: 1.0698x; 1.0060x over previous
//
#include <hip/hip_runtime.h>

#define LOG2E 1.4426950408889634f

typedef __bf16 bf16x8 __attribute__((ext_vector_type(8)));
typedef short s16x4 __attribute__((ext_vector_type(4)));
typedef float f32x4 __attribute__((ext_vector_type(4)));

#define BB 2
#define NN 2048
#define CC 384
#define NH 12
#define HD 32

__device__ __forceinline__ unsigned short f2bf(float f) {
  __bf16 h = (__bf16)f;
  return __builtin_bit_cast(unsigned short, h);
}

__device__ __forceinline__ bf16x8 ldg_bf8(const unsigned short* p) {
  uint4 v = *reinterpret_cast<const uint4*>(p);
  return __builtin_bit_cast(bf16x8, v);
}

// fast 2^x: raw v_exp_f32 (args here are bounded ~±48, no denorm fixup needed)
__device__ __forceinline__ float fexp2(float x) {
#if __has_builtin(__builtin_amdgcn_exp2f)
  return __builtin_amdgcn_exp2f(x);
#else
  return exp2f(x);
#endif
}

// pack 4 floats -> 4 bf16 via v_cvt_pk_bf16_f32 when available
__device__ __forceinline__ s16x4 pack_bf4(float a, float b, float c, float d) {
#if __has_builtin(__builtin_amdgcn_cvt_pk_bf16_f32)
  auto lo = __builtin_amdgcn_cvt_pk_bf16_f32(a, b);
  auto hi = __builtin_amdgcn_cvt_pk_bf16_f32(c, d);
  uint2 u = {__builtin_bit_cast(unsigned int, lo),
             __builtin_bit_cast(unsigned int, hi)};
  return __builtin_bit_cast(s16x4, u);
#else
  s16x4 r = {(short)f2bf(a), (short)f2bf(b), (short)f2bf(c), (short)f2bf(d)};
  return r;
#endif
}

// async global->LDS DMA, 16B per lane; LDS dest = wave-uniform base + lane*16
typedef __attribute__((address_space(1))) const void gas_void;
typedef __attribute__((address_space(3))) void las_void;
__device__ __forceinline__ void gload_lds16(const void* g, void* l) {
  __builtin_amdgcn_global_load_lds((gas_void*)(unsigned long long)g,
                                   (las_void*)(unsigned long long)l, 16, 0, 0);
}

__device__ __forceinline__ f32x4 mfma32(bf16x8 a, bf16x8 b, f32x4 c) {
  return __builtin_amdgcn_mfma_f32_16x16x32_bf16(a, b, c, 0, 0, 0);
}

// 16x16x16 bf16 MFMA (A,B = 4 bf16/lane: X[m|n=lane&15][k=(lane>>4)*4+j];
// C/D: row=(lane>>4)*4+r, col=lane&15). Host pass must not see the builtin.
__device__ __forceinline__ f32x4 mfma16(s16x4 a, s16x4 b, f32x4 c) {
#if defined(__HIP_DEVICE_COMPILE__)
#if __has_builtin(__builtin_amdgcn_mfma_f32_16x16x16bf16_1k)
  return __builtin_amdgcn_mfma_f32_16x16x16bf16_1k(a, b, c, 0, 0, 0);
#else
  asm volatile("v_mfma_f32_16x16x16_bf16 %0, %1, %2, %0"
               : "+v"(c) : "v"(a), "v"(b));
  return c;
#endif
#else
  return c;  // host type-check stub
#endif
}

// ------- prep: fp32->bf16 casts, 8 elems/thread (G13 vectorized) -------------
// Segments (elems): x 1572864 | q_w 147456 | kv_w 294912 | proj_w 147456 |
// pos_bias 24576. Total 2187264 = 1068 blocks * 256 thr * 8.
__global__ __launch_bounds__(256) void prep_kernel(
    const float* __restrict__ x, const float* __restrict__ q_w,
    const float* __restrict__ kv_w, const float* __restrict__ proj_w,
    const float* __restrict__ pos_bias, unsigned short* __restrict__ xb,
    unsigned short* __restrict__ qwb, unsigned short* __restrict__ kvwb,
    unsigned short* __restrict__ pwb, float* __restrict__ bias2) {
  long i = (long)(blockIdx.x * 256 + threadIdx.x) * 8;
  auto cast8 = [&](const float* s, unsigned short* d, long off) {
    float4 a = *reinterpret_cast<const float4*>(s + off);
    float4 b = *reinterpret_cast<const float4*>(s + off + 4);
    s16x4 lo = pack_bf4(a.x, a.y, a.z, a.w);
    s16x4 hi = pack_bf4(b.x, b.y, b.z, b.w);
    uint2 l = __builtin_bit_cast(uint2, lo), h = __builtin_bit_cast(uint2, hi);
    uint4 o = {l.x, l.y, h.x, h.y};
    *reinterpret_cast<uint4*>(d + off) = o;
  };
  if (i < 1572864) { cast8(x, xb, i); return; }
  i -= 1572864;
  if (i < 147456) { cast8(q_w, qwb, i); return; }
  i -= 147456;
  if (i < 294912) { cast8(kv_w, kvwb, i); return; }
  i -= 294912;
  if (i < 147456) { cast8(proj_w, pwb, i); return; }
  i -= 147456;
  float4 a = *reinterpret_cast<const float4*>(pos_bias + i);
  float4 b = *reinterpret_cast<const float4*>(pos_bias + i + 4);
  a.x *= LOG2E; a.y *= LOG2E; a.z *= LOG2E; a.w *= LOG2E;
  b.x *= LOG2E; b.y *= LOG2E; b.z *= LOG2E; b.w *= LOG2E;
  *reinterpret_cast<float4*>(bias2 + i) = a;
  *reinterpret_cast<float4*>(bias2 + i + 4) = b;
}

// ------- fused QKV GEMM + l2norm, LDS-staged (m97 structure + T2 swizzle) ----
// Grid (64, NH). Block tile 64M x 96N (head h: q|k|v 32-col slices), BK=64.
// V output uses the BLOCKED layout VT[pair][nblk=n/32][d=32][ns=n%32] so the
// attn kernel's V tiles are contiguous 2KB blocks (one per 32 krows).
__global__ __launch_bounds__(256, 4) void gemm_qkv_norm_kernel(
    const unsigned short* __restrict__ xb, const unsigned short* __restrict__ qwb,
    const unsigned short* __restrict__ kvwb, const float* __restrict__ q_b,
    const float* __restrict__ kv_b, const float* __restrict__ qe,
    const float* __restrict__ temperature, unsigned short* __restrict__ Qs,
    unsigned short* __restrict__ Kn, unsigned short* __restrict__ VT) {
  __shared__ alignas(16) char smem[2][20480];
  int wave = threadIdx.x >> 6, lane = threadIdx.x & 63;
  int c = lane & 15, quad = lane >> 4;
  int h = blockIdx.y;
  int m0b = blockIdx.x * 64;
  int cid = wave * 64 + lane;

  auto stage = [&](int buf, int kk) {
    char* base = smem[buf];
#pragma unroll
    for (int j = 0; j < 2; ++j) {  // A: 512 chunks (64 rows x 128B)
      int chunk = j * 256 + cid;
      int row = chunk >> 3, e = chunk & 7;
      gload_lds16(xb + (long)(m0b + row) * CC + kk + (e ^ (row & 7)) * 8,
                  base + j * 4096 + wave * 1024);
    }
#pragma unroll
    for (int j = 0; j < 3; ++j) {  // B: 768 chunks (96 rows x 128B)
      int chunk = j * 256 + cid;
      int row = chunk >> 3, e = chunk & 7;
      const unsigned short* src;
      if (row < 32)      src = qwb + (long)(h * 32 + row) * CC;
      else if (row < 64) src = kvwb + (long)(h * 32 + (row - 32)) * CC;
      else               src = kvwb + (long)(CC + h * 32 + (row - 64)) * CC;
      gload_lds16(src + kk + (e ^ (row & 7)) * 8,
                  base + 8192 + j * 4096 + wave * 1024);
    }
  };

  f32x4 acc[6] = {};
  auto compute = [&](int buf) {
    const char* base = smem[buf];
#pragma unroll
    for (int kh = 0; kh < 2; ++kh) {
      int sa = ((kh * 4 + quad) ^ (c & 7)) * 16;  // swizzled slot
      bf16x8 a = *(const bf16x8*)(base + (wave * 16 + c) * 128 + sa);
#pragma unroll
      for (int t = 0; t < 6; ++t) {
        bf16x8 b = *(const bf16x8*)(base + 8192 + (t * 16 + c) * 128 + sa);
        acc[t] = mfma32(a, b, acc[t]);
      }
    }
  };

  stage(0, 0);
#pragma unroll 1
  for (int s = 0; s < 6; ++s) {
    __syncthreads();
    if (s < 5) stage((s + 1) & 1, (s + 1) * 64);
    compute(s & 1);
  }

  // epilogue: bias + l2norm(q,k) + qe/scale + stores
  int m0 = m0b + wave * 16;
  float qb0 = q_b[h * 32 + c], qb1 = q_b[h * 32 + 16 + c];
  float kb0 = kv_b[h * 32 + c], kb1 = kv_b[h * 32 + 16 + c];
  float vb0 = kv_b[CC + h * 32 + c], vb1 = kv_b[CC + h * 32 + 16 + c];
  float qe0 = qe[h * HD + c], qe1 = qe[h * HD + 16 + c];
  float sc = log1pf(expf(temperature[h])) * 11.0f;  // softplus * log2(N)
  int b = m0 >> 11;
  int nb = (m0 & 2047) + quad * 4;
  int pair = b * NH + h;
  unsigned short* qsb = Qs + ((long)pair * NN + nb) * HD;
  unsigned short* knb = Kn + ((long)pair * NN + nb) * HD;
  ushort4 vp0, vp1;
#pragma unroll
  for (int r = 0; r < 4; ++r) {
    float q0 = acc[0][r] + qb0, q1 = acc[1][r] + qb1;
    float k0 = acc[2][r] + kb0, k1 = acc[3][r] + kb1;
    float v0 = acc[4][r] + vb0, v1 = acc[5][r] + vb1;
    float qs = q0 * q0 + q1 * q1, ks = k0 * k0 + k1 * k1;
#pragma unroll
    for (int off = 8; off; off >>= 1) {
      qs += __shfl_xor(qs, off);
      ks += __shfl_xor(ks, off);
    }
    float qi = 1.0f / fmaxf(sqrtf(qs), 1e-12f);
    float ki = 1.0f / fmaxf(sqrtf(ks), 1e-12f);
    qsb[r * HD + c] = f2bf((q0 * qi + qe0) * sc);
    qsb[r * HD + 16 + c] = f2bf((q1 * qi + qe1) * sc);
    knb[r * HD + c] = f2bf(k0 * ki);
    knb[r * HD + 16 + c] = f2bf(k1 * ki);
    ((unsigned short*)&vp0)[r] = f2bf(v0);
    ((unsigned short*)&vp1)[r] = f2bf(v1);
  }
  // blocked VT store: offset(pair,d,n) = (pair*64 + n/32)*1024 + d*32 + n%32.
  // nb%4==0 so the 4 consecutive n of vp stay inside one 32-block (ushort4 ok).
  long vbo = ((long)pair * 64 + (nb >> 5)) * 1024 + (nb & 31);
  *reinterpret_cast<ushort4*>(VT + vbo + c * 32) = vp0;
  *reinterpret_cast<ushort4*>(VT + vbo + (16 + c) * 32) = vp1;
}

// -------- attention: K-SPLIT across waves, barrier-free main loop ------------
// Grid 768 x 256. Wave w owns PRIVATE k-range [w*512,(w+1)*512), 16 tiles of
// KVBLK=32, double-buffered in wave-private LDS. VT blocked (contiguous 2KB V
// tiles). NEW vs R7: softmax row-sum accumulated on the (idle) MFMA pipe via
// an all-ones A operand -- ro = mfma16(ones, pf, ro) gives every C row =
// column-sum of P -- deleting 3 VALU adds/frag-step + all rs shuffles from the
// busy VALU pipe, and making denominator consistent with the bf16 P numerator.
// LDS: 4 waves x 8KB dbuf + 8KB bias = 40,960 B -> 3 blocks/CU, zero tail.
__global__ __launch_bounds__(256, 3) void attn_kernel(
    const unsigned short* __restrict__ Qs, const unsigned short* __restrict__ Kn,
    const unsigned short* __restrict__ VT, const float* __restrict__ bias2,
    unsigned short* __restrict__ ao) {
  __shared__ alignas(16) char smem[40960];  // [w*8192: dbuf (K2K|V2K)x2][32768: bias 8K]
  int wave = threadIdx.x >> 6, lane = threadIdx.x & 63;
  int c = lane & 15, quad = lane >> 4;
  int id = blockIdx.x;
  int xcd = id & 7, rr = id >> 3;
  int pair = (rr >> 5) * 8 + xcd;   // 3 pairs per XCD
  int qt = rr & 31;
  int h = pair % NH, b = pair / NH;
  const unsigned short* Qp = Qs + (long)pair * NN * HD;
  const char* Kg0 = (const char*)(Kn + (long)pair * NN * HD) + wave * 32768;
  // V: blocked layout; this wave's 16 tiles start at nblk = wave*16
  const char* Vg0 = (const char*)(VT) + ((long)pair * 64 + wave * 16) * 2048;
  const char* bp = (const char*)(bias2 + h * NN);
  int q0 = qt * 64;
  bf16x8 qf0 = ldg_bf8(Qp + (long)(q0 + c) * HD + quad * 8);
  bf16x8 qf1 = ldg_bf8(Qp + (long)(q0 + 16 + c) * HD + quad * 8);
  bf16x8 qf2 = ldg_bf8(Qp + (long)(q0 + 32 + c) * HD + quad * 8);
  bf16x8 qf3 = ldg_bf8(Qp + (long)(q0 + 48 + c) * HD + quad * 8);
  f32x4 o00 = {}, o10 = {}, o01 = {}, o11 = {};
  f32x4 o02 = {}, o12 = {}, o03 = {}, o13 = {};
  f32x4 ro0 = {}, ro1 = {}, ro2 = {}, ro3 = {};  // MFMA-ones row sums
  const s16x4 vone = {(short)0x3F80, (short)0x3F80,
                      (short)0x3F80, (short)0x3F80};  // bf16 1.0 x4

  char* sw = smem + wave * 8192;              // private dbuf
  char* biasl = smem + 32768;
  const int koff = (c * 4 + quad) * 16;       // K within-chunk source perm
  int vd = lane >> 2, ve = lane & 3;          // V unit coords within tile
  int ves = ve ^ (vd & 3);                    // source swizzle (involution)

  // stage tile i (32 krows) of this wave's range into private buf
  auto stage = [&](int buf, int i) {
    char* tb = sw + buf * 4096;
    const char* Kg = Kg0 + i * 2048;          // 32 rows x 64 B (contiguous)
    const char* Vg = Vg0 + i * 2048;          // contiguous 2KB V tile
#pragma unroll
    for (int j = 0; j < 2; ++j) {
      gload_lds16(Kg + j * 1024 + koff, tb + j * 1024);
      gload_lds16(Vg + (long)(j * 16 + vd) * 64 + ves * 16,
                  tb + 2048 + j * 1024);
    }
  };

#define FRAG_STEP(QF, O0, O1, RO)              \
  {                                            \
    f32x4 s = mfma32(kf, QF, bbv);             \
    float p0 = fexp2(s[0]), p1 = fexp2(s[1]);  \
    float p2 = fexp2(s[2]), p3 = fexp2(s[3]);  \
    s16x4 pf = pack_bf4(p0, p1, p2, p3);       \
    RO = mfma16(vone, pf, RO);                 \
    O0 = mfma16(vlo, pf, O0);                  \
    O1 = mfma16(vhi, pf, O1);                  \
  }

  auto compute = [&](int buf, int i) {
    const char* kb = sw + buf * 4096 + lane * 16;
    const char* vb = sw + buf * 4096 + 2048;
    const char* bl = biasl + wave * 2048 + i * 128 + quad * 16;
#pragma unroll
    for (int t8 = 0; t8 < 2; ++t8) {
      bf16x8 kf = *(const bf16x8*)(kb + t8 * 1024);
      f32x4 bbv = *(const f32x4*)(bl + t8 * 64);  // 4-addr broadcast (free)
      int sl = ((t8 * 2 + (quad >> 1)) ^ (c & 3)) * 16 + (quad & 1) * 8;
      s16x4 vlo = *(const s16x4*)(vb + c * 64 + sl);
      s16x4 vhi = *(const s16x4*)(vb + 1024 + c * 64 + sl);
      FRAG_STEP(qf0, o00, o10, ro0)
      FRAG_STEP(qf1, o01, o11, ro1)
      FRAG_STEP(qf2, o02, o12, ro2)
      FRAG_STEP(qf3, o03, o13, ro3)
    }
  };
#undef FRAG_STEP

  // prologue: bias (shared, 2 loads/lane) + first private tile; one full drain
#pragma unroll
  for (int j = 0; j < 2; ++j)
    gload_lds16(bp + j * 4096 + wave * 1024 + lane * 16,
                biasl + j * 4096 + wave * 1024);
  stage(0, 0);
  __syncthreads();

  // barrier-free main loop: issue next private tile, wait only for current
  // (vmcnt(4): next tile's 4 DMAs stay in flight), compute.
#pragma unroll 1
  for (int i = 0; i < 16; ++i) {
    asm volatile("s_waitcnt lgkmcnt(0)" ::: "memory");  // prior buf reads done
    if (i < 15) {
      stage((i + 1) & 1, i + 1);
      asm volatile("s_waitcnt vmcnt(4)" ::: "memory");
    } else {
      asm volatile("s_waitcnt vmcnt(0)" ::: "memory");
    }
    __builtin_amdgcn_sched_barrier(0);  // rule #18: no ds_read hoist past wait
    compute(i & 1, i);
  }

  // ---- cross-wave combine: comb[frag][w][comp][lane] f32, 36,864 B ----------
  // ro*[0] already holds the FULL per-q (col c) sum over this wave's 512
  // krows (all C rows of the ones-MFMA are identical) -> no shuffles needed.
  __syncthreads();
  float* comb = (float*)smem;
#define PUT(F, O0, O1, RS)                                          \
  {                                                                 \
    float* p = comb + ((F * 4 + wave) * 9) * 64 + lane;             \
    p[0] = O0[0]; p[64] = O0[1]; p[128] = O0[2]; p[192] = O0[3];    \
    p[256] = O1[0]; p[320] = O1[1]; p[384] = O1[2]; p[448] = O1[3]; \
    p[512] = RS;                                                    \
  }
  PUT(0, o00, o10, ro0[0])
  PUT(1, o01, o11, ro1[0])
  PUT(2, o02, o12, ro2[0])
  PUT(3, o03, o13, ro3[0])
#undef PUT
  __syncthreads();
  // wave w finalizes frag w (q-rows q0 + w*16 .. +16)
  f32x4 A0 = {}, A1 = {};
  float AR = 0.f;
#pragma unroll
  for (int w2 = 0; w2 < 4; ++w2) {
    const float* p = comb + ((wave * 4 + w2) * 9) * 64 + lane;
    A0[0] += p[0]; A0[1] += p[64]; A0[2] += p[128]; A0[3] += p[192];
    A1[0] += p[256]; A1[1] += p[320]; A1[2] += p[384]; A1[3] += p[448];
    AR += p[512];
  }
  float inv = 1.0f / AR;  // AR is already the full 2048-row sum for q=c
  int qr = q0 + wave * 16 + c;
  unsigned short* op = ao + (long)(b * NN + qr) * CC + h * HD + quad * 4;
  ushort4 s0, s1;
#pragma unroll
  for (int r = 0; r < 4; ++r) {
    ((unsigned short*)&s0)[r] = f2bf(A0[r] * inv);
    ((unsigned short*)&s1)[r] = f2bf(A1[r] * inv);
  }
  *reinterpret_cast<ushort4*>(op) = s0;
  *reinterpret_cast<ushort4*>(op + 16) = s1;
}

// ---------------- proj: out = ao @ proj_w^T + proj_b, LDS-staged -------------
// Grid (64, 12). Block tile 64M x 32N, BK=64 -> 768 blocks = exactly 3/CU.
__global__ __launch_bounds__(256, 4) void proj_kernel(
    const unsigned short* __restrict__ ab, const unsigned short* __restrict__ pwb,
    const float* __restrict__ proj_b, float* __restrict__ out) {
  __shared__ alignas(16) char smem[2][12288];
  int wave = threadIdx.x >> 6, lane = threadIdx.x & 63;
  int c = lane & 15, quad = lane >> 4;
  int m0b = blockIdx.x * 64;
  int n0 = blockIdx.y * 32;
  int cid = wave * 64 + lane;

  auto stage = [&](int buf, int kk) {
    char* base = smem[buf];
#pragma unroll
    for (int j = 0; j < 2; ++j) {  // A: 512 chunks (64 rows x 128B)
      int chunk = j * 256 + cid;
      int row = chunk >> 3, e = chunk & 7;
      gload_lds16(ab + (long)(m0b + row) * CC + kk + (e ^ (row & 7)) * 8,
                  base + j * 4096 + wave * 1024);
    }
    {  // B: 256 chunks (32 rows x 128B)
      int row = cid >> 3, e = cid & 7;
      gload_lds16(pwb + (long)(n0 + row) * CC + kk + (e ^ (row & 7)) * 8,
                  base + 8192 + wave * 1024);
    }
  };

  f32x4 acc[2] = {};
  auto compute = [&](int buf) {
    const char* base = smem[buf];
#pragma unroll
    for (int kh = 0; kh < 2; ++kh) {
      int sa = ((kh * 4 + quad) ^ (c & 7)) * 16;  // swizzled slot
      bf16x8 a = *(const bf16x8*)(base + (wave * 16 + c) * 128 + sa);
#pragma unroll
      for (int t = 0; t < 2; ++t) {
        bf16x8 b = *(const bf16x8*)(base + 8192 + (t * 16 + c) * 128 + sa);
        acc[t] = mfma32(a, b, acc[t]);
      }
    }
  };

  stage(0, 0);
#pragma unroll 1
  for (int s = 0; s < 6; ++s) {
    __syncthreads();
    if (s < 5) stage((s + 1) & 1, (s + 1) * 64);
    compute(s & 1);
  }

  int m0 = m0b + wave * 16;
#pragma unroll
  for (int t = 0; t < 2; ++t) {
    int o = n0 + t * 16 + c;
    float bv = proj_b[o];
#pragma unroll
    for (int r = 0; r < 4; ++r) {
      out[(long)(m0 + quad * 4 + r) * CC + o] = acc[t][r] + bv;
    }
  }
}

extern "C" void kernel_launch(void* const* d_in, const int* in_sizes, int n_in,
                              void* d_out, int out_size, void* d_ws, size_t ws_size,
                              hipStream_t stream) {
  const float* x = (const float*)d_in[0];
  const float* q_w = (const float*)d_in[1];
  const float* q_b = (const float*)d_in[2];
  const float* kv_w = (const float*)d_in[3];
  const float* kv_b = (const float*)d_in[4];
  const float* qe = (const float*)d_in[5];
  const float* temp = (const float*)d_in[6];
  const float* pos_bias = (const float*)d_in[7];
  const float* proj_w = (const float*)d_in[8];
  const float* proj_b = (const float*)d_in[9];
  float* out = (float*)d_out;

  char* ws = (char*)d_ws;
  unsigned short* xb = (unsigned short*)(ws + 0);          // 3,145,728 B
  unsigned short* qwb = (unsigned short*)(ws + 3145728);   //   294,912 B
  unsigned short* kvwb = (unsigned short*)(ws + 3440640);  //   589,824 B
  unsigned short* pwb = (unsigned short*)(ws + 4030464);   //   294,912 B
  unsigned short* Qs = (unsigned short*)(ws + 4325376);    // 3,145,728 B
  unsigned short* Kn = (unsigned short*)(ws + 7471104);    // 3,145,728 B
  unsigned short* VT = (unsigned short*)(ws + 10616832);   // 3,145,728 B
  unsigned short* ao = (unsigned short*)(ws + 13762560);   // 3,145,728 B
  float* bias2 = (float*)(ws + 16908288);                  //    98,304 B -> 17 MB

  prep_kernel<<<1068, 256, 0, stream>>>(x, q_w, kv_w, proj_w, pos_bias, xb, qwb,
                                        kvwb, pwb, bias2);
  gemm_qkv_norm_kernel<<<dim3(64, NH), 256, 0, stream>>>(xb, qwb, kvwb, q_b, kv_b,
                                                         qe, temp, Qs, Kn, VT);
  attn_kernel<<<768, 256, 0, stream>>>(Qs, Kn, VT, bias2, ao);
  proj_kernel<<<dim3(64, 12), 256, 0, stream>>>(ao, pwb, proj_b, out);
}